// Round 3
// 567.990 us; speedup vs baseline: 1.0275x; 1.0275x over previous
//
#include <hip/hip_runtime.h>

// Flash-attention fwd, B=4 H=16 S=2048 D=128, fp32 in/out, bf16 MFMA compute.
// Round 5 resubmit (previous bench was an infra failure, no signal).
// Bisect: keep ONLY the staging rework from round 4 — prepass builds
// MFMA-ready bf16 tile images (V transposed; 16B blocks XOR-swizzled so the
// unpadded LDS tile is conflict-free), main kernel stages via
// global_load_lds_dwordx4 (zero staging VALU / registers). Softmax numerics
// bit-exact to the round-3-passing path (__expf, f2bf, always-rescale).

#define S_LEN 2048
#define HD 128
#define BQ 64
#define BK 64
#define NT (S_LEN / BK)          // 32
#define TILE_SH (BK * HD)        // 8192 shorts = 16 KB per staged tile image
#define PLD 68                   // P LDS row stride -> conflict-free
#define NBH 64

typedef __attribute__((ext_vector_type(8))) short bf16x8;
typedef __attribute__((ext_vector_type(4))) float f32x4;
typedef __attribute__((ext_vector_type(4))) short s16x4;

static __device__ __forceinline__ unsigned short f2bf(float f) {
    unsigned int u = __builtin_bit_cast(unsigned int, f);
    u += 0x7fffu + ((u >> 16) & 1u);   // round-to-nearest-even
    return (unsigned short)(u >> 16);
}

// global -> LDS direct DMA, 16B per lane; LDS dest = wave-uniform base + lane*16
static __device__ __forceinline__ void gload16(const short* g, short* l) {
    __builtin_amdgcn_global_load_lds(
        (const __attribute__((address_space(1))) unsigned int*)(const void*)g,
        (__attribute__((address_space(3))) unsigned int*)(void*)l,
        16, 0, 0);
}

// ---------------------------------------------------------------------------
// Prepass: build bf16 tile images in workspace.
//   K image [bh][kt][row 0..63][cb 0..15][8]: phys block cb holds logical
//     block cb^(row&7) of K[row] (8 bf16 each).
//   V image [bh][kt][d 0..127][cb 0..7][8]: phys block cb holds
//     V[kt*64 + ((cb^(d&7))*8) .. +8][d].
// Reader XORs the same row bits -> conflict-free ds_read_b128 with NO padding
// (rows stay 16B-multiples so global_load_lds destinations are linear).
// ---------------------------------------------------------------------------
__global__ __launch_bounds__(256)
void prep_kernel(const float* __restrict__ kg0, const float* __restrict__ vg0,
                 short* __restrict__ wsk, short* __restrict__ wsv)
{
    const int kt = blockIdx.x;
    const int bh = blockIdx.y;
    const int t  = threadIdx.x;
    if (blockIdx.z == 0) {
        const float* src = kg0 + ((size_t)bh * S_LEN + kt * BK) * HD;
        short* dst = wsk + ((size_t)bh * NT + kt) * TILE_SH;
        #pragma unroll
        for (int i = 0; i < 4; ++i) {
            const int c = t + 256 * i;
            const int row = c >> 4, cb = c & 15;
            const float* s = src + row * HD + ((cb ^ (row & 7)) << 3);
            const f32x4 a = *(const f32x4*)s;
            const f32x4 b = *(const f32x4*)(s + 4);
            bf16x8 o;
            #pragma unroll
            for (int j = 0; j < 4; ++j) {
                o[j]     = (short)f2bf(a[j]);
                o[j + 4] = (short)f2bf(b[j]);
            }
            *(bf16x8*)(dst + (size_t)c * 8) = o;
        }
    } else {
        __shared__ short lv[BK * 136];    // [kk][d] staging for the transpose
        const float* src = vg0 + ((size_t)bh * S_LEN + kt * BK) * HD;
        short* dst = wsv + ((size_t)bh * NT + kt) * TILE_SH;
        #pragma unroll
        for (int p = 0; p < 2; ++p) {
            const int kk = (t >> 3) + p * 32;
            const int d0 = (t & 7) * 16;
            const float* s = src + kk * HD + d0;
            #pragma unroll
            for (int g = 0; g < 2; ++g) {
                const f32x4 a = *(const f32x4*)(s + g * 8);
                const f32x4 b = *(const f32x4*)(s + g * 8 + 4);
                bf16x8 o;
                #pragma unroll
                for (int j = 0; j < 4; ++j) {
                    o[j]     = (short)f2bf(a[j]);
                    o[j + 4] = (short)f2bf(b[j]);
                }
                *(bf16x8*)&lv[kk * 136 + d0 + g * 8] = o;
            }
        }
        __syncthreads();
        #pragma unroll
        for (int i = 0; i < 4; ++i) {
            const int c = t + 256 * i;
            const int d = c >> 3, cb = c & 7;
            const int kk0 = (cb ^ (d & 7)) << 3;
            bf16x8 o;
            #pragma unroll
            for (int j = 0; j < 8; ++j) o[j] = lv[(kk0 + j) * 136 + d];
            *(bf16x8*)(dst + (size_t)c * 8) = o;
        }
    }
}

// ---------------------------------------------------------------------------
// Main kernel (workspace path) — round-3 softmax numerics, round-4 staging.
// ---------------------------------------------------------------------------
__global__ __launch_bounds__(256, 2)
void fattn_ws_kernel(const short* __restrict__ wsk, const short* __restrict__ wsv,
                     const float* __restrict__ qg0, const float* __restrict__ maskg,
                     float* __restrict__ outg0)
{
    __shared__ short k_lds[2][TILE_SH];   // double-buffered K tile image
    __shared__ short v_lds[TILE_SH];      // single-buffered V^T tile image
    __shared__ short p_lds[4 * 16 * PLD]; // per-wave P tile

    const int tid  = threadIdx.x;
    const int wave = tid >> 6;
    const int lane = tid & 63;
    const int quad = lane >> 4;
    const int l16  = lane & 15;

    const int bh = blockIdx.x;            // fast dim: co-resident blocks share K/V
    const int q0 = blockIdx.y * BQ;

    const float* qg   = qg0 + (size_t)bh * S_LEN * HD;
    float*       outg = outg0 + (size_t)bh * S_LEN * HD;
    const short* ktiles = wsk + (size_t)bh * NT * TILE_SH;
    const short* vtiles = wsv + (size_t)bh * NT * TILE_SH;

    const int soff = tid * 8;             // per-thread offset in tile (shorts)
    const int loff = (tid & ~63) * 8;     // wave-uniform LDS offset (shorts)

    // issue K tile 0 immediately (drained by first barrier)
    #pragma unroll
    for (int p = 0; p < 4; ++p)
        gload16(ktiles + p * 2048 + soff, &k_lds[0][p * 2048 + loff]);

    // Q A-fragments: m = l16, k = ks*32 + quad*8 + j  (held for whole kernel)
    bf16x8 qf[4];
    {
        const float* qrow = qg + (size_t)(q0 + wave * 16 + l16) * HD + quad * 8;
        #pragma unroll
        for (int ks = 0; ks < 4; ++ks) {
            const f32x4 a = *(const f32x4*)(qrow + ks * 32);
            const f32x4 b = *(const f32x4*)(qrow + ks * 32 + 4);
            #pragma unroll
            for (int j = 0; j < 4; ++j) {
                qf[ks][j]     = (short)f2bf(a[j]);
                qf[ks][j + 4] = (short)f2bf(b[j]);
            }
        }
    }

    float m_run[4], l_run[4];
    f32x4 oacc[8];
    #pragma unroll
    for (int r = 0; r < 4; ++r) { m_run[r] = -3.0e38f; l_run[r] = 0.0f; }
    #pragma unroll
    for (int d = 0; d < 8; ++d) oacc[d] = (f32x4){0.f, 0.f, 0.f, 0.f};

    const float scale = 0.088388347648318447f;  // 1/sqrt(128)
    const float* mrow = maskg + (size_t)(q0 + wave * 16 + quad * 4) * S_LEN + l16;

    float mpre[4][4];
    #pragma unroll
    for (int nt = 0; nt < 4; ++nt)
        #pragma unroll
        for (int r = 0; r < 4; ++r)
            mpre[nt][r] = mrow[(size_t)r * S_LEN + nt * 16];

    // LDS fragment-read bases (shorts). Swizzled block index decomposes into
    // base ^ (ks-bit) + immediates -> zero per-iteration address VALU.
    const int kb0 = l16 * 128 + ((quad ^ (l16 & 3)) << 3) + (((l16 >> 2) & 1) << 5);
    const int kb1 = kb0 ^ 32;
    const int vb0 = l16 * 64  + ((quad ^ (l16 & 3)) << 3) + (((l16 >> 2) & 1) << 5);
    const int vb1 = vb0 ^ 32;
    short* const pw = &p_lds[wave * 16 * PLD];

    for (int kt = 0; kt < NT; ++kt) {
        const short* kcur = k_lds[kt & 1];
        asm volatile("s_waitcnt vmcnt(0)" ::: "memory");  // K[kt] DMA landed
        __syncthreads();

        // issue V[kt]; latency hidden under QK^T + softmax
        #pragma unroll
        for (int p = 0; p < 4; ++p)
            gload16(vtiles + (size_t)kt * TILE_SH + p * 2048 + soff,
                    &v_lds[p * 2048 + loff]);

        // ---- S = Q K^T ----
        f32x4 sf[4];
        #pragma unroll
        for (int nt = 0; nt < 4; ++nt) {
            f32x4 acc = (f32x4){0.f, 0.f, 0.f, 0.f};
            #pragma unroll
            for (int ks = 0; ks < 4; ++ks) {
                const bf16x8 kf = *(const bf16x8*)
                    &kcur[((ks & 1) ? kb1 : kb0) + (ks >> 1) * 64 + nt * 2048];
                acc = __builtin_amdgcn_mfma_f32_16x16x32_bf16(qf[ks], kf, acc, 0, 0, 0);
            }
            sf[nt] = acc;
        }

        float sv[4][4];
        float mx[4] = {-3.0e38f, -3.0e38f, -3.0e38f, -3.0e38f};
        #pragma unroll
        for (int nt = 0; nt < 4; ++nt)
            #pragma unroll
            for (int r = 0; r < 4; ++r) {
                const float s = sf[nt][r] * scale + mpre[nt][r];
                sv[nt][r] = s;
                mx[r] = fmaxf(mx[r], s);
            }

        #pragma unroll
        for (int r = 0; r < 4; ++r) {
            mx[r] = fmaxf(mx[r], __shfl_xor(mx[r], 1, 16));
            mx[r] = fmaxf(mx[r], __shfl_xor(mx[r], 2, 16));
            mx[r] = fmaxf(mx[r], __shfl_xor(mx[r], 4, 16));
            mx[r] = fmaxf(mx[r], __shfl_xor(mx[r], 8, 16));
        }

        float alpha[4], pl[4];
        #pragma unroll
        for (int r = 0; r < 4; ++r) {
            const float mnew = fmaxf(m_run[r], mx[r]);
            alpha[r] = __expf(m_run[r] - mnew);
            m_run[r] = mnew;
            pl[r] = 0.f;
        }

        short pb[4][4];
        #pragma unroll
        for (int nt = 0; nt < 4; ++nt)
            #pragma unroll
            for (int r = 0; r < 4; ++r) {
                const float p = __expf(sv[nt][r] - m_run[r]);
                const unsigned short b = f2bf(p);
                pb[nt][r] = (short)b;
                // accumulate l from the *rounded* p so normalization matches PV
                pl[r] += __builtin_bit_cast(float, (unsigned int)b << 16);
            }
        #pragma unroll
        for (int r = 0; r < 4; ++r) {
            pl[r] += __shfl_xor(pl[r], 1, 16);
            pl[r] += __shfl_xor(pl[r], 2, 16);
            pl[r] += __shfl_xor(pl[r], 4, 16);
            pl[r] += __shfl_xor(pl[r], 8, 16);
            l_run[r] = l_run[r] * alpha[r] + pl[r];
        }
        #pragma unroll
        for (int d = 0; d < 8; ++d)
            #pragma unroll
            for (int r = 0; r < 4; ++r)
                oacc[d][r] *= alpha[r];

        // ---- P: C-layout -> LDS -> A-layout (per-wave region, no barrier) ----
        #pragma unroll
        for (int nt = 0; nt < 4; ++nt)
            #pragma unroll
            for (int r = 0; r < 4; ++r)
                pw[(quad * 4 + r) * PLD + nt * 16 + l16] = pb[nt][r];

        bf16x8 pf[2];
        #pragma unroll
        for (int ks = 0; ks < 2; ++ks) {
            const s16x4 lo = *(const s16x4*)&pw[l16 * PLD + ks * 32 + quad * 8];
            const s16x4 hi = *(const s16x4*)&pw[l16 * PLD + ks * 32 + quad * 8 + 4];
            pf[ks] = __builtin_shufflevector(lo, hi, 0, 1, 2, 3, 4, 5, 6, 7);
        }

        asm volatile("s_waitcnt vmcnt(0)" ::: "memory");  // V[kt] DMA landed
        __syncthreads();

        // issue K[kt+1] + next mask tile; consumed next iteration (hidden by PV)
        const int nk = (kt + 1) & (NT - 1);
        #pragma unroll
        for (int p = 0; p < 4; ++p)
            gload16(ktiles + (size_t)nk * TILE_SH + p * 2048 + soff,
                    &k_lds[nk & 1][p * 2048 + loff]);
        const int nb = nk * BK;
        #pragma unroll
        for (int nt = 0; nt < 4; ++nt)
            #pragma unroll
            for (int r = 0; r < 4; ++r)
                mpre[nt][r] = mrow[(size_t)r * S_LEN + nb + nt * 16];

        // ---- O += P V ----
        #pragma unroll
        for (int dt = 0; dt < 8; ++dt) {
            #pragma unroll
            for (int ks = 0; ks < 2; ++ks) {
                const bf16x8 vf = *(const bf16x8*)&v_lds[(ks ? vb1 : vb0) + dt * 1024];
                oacc[dt] = __builtin_amdgcn_mfma_f32_16x16x32_bf16(pf[ks], vf, oacc[dt], 0, 0, 0);
            }
        }
    }

    // ---- epilogue: normalize and store ----
    const int orow0 = q0 + wave * 16 + quad * 4;
    #pragma unroll
    for (int r = 0; r < 4; ++r) {
        const float inv = 1.0f / l_run[r];
        float* orow = outg + (size_t)(orow0 + r) * HD + l16;
        #pragma unroll
        for (int d = 0; d < 8; ++d)
            orow[d * 16] = oacc[d][r] * inv;
    }
}

// ---------------------------------------------------------------------------
// Legacy kernel (round 3, proven) — fallback if workspace is too small.
// ---------------------------------------------------------------------------
#define KLD 136
#define VLD 72

__global__ __launch_bounds__(256, 2)
void fattn_legacy(const float* __restrict__ qg0, const float* __restrict__ kg0,
                  const float* __restrict__ vg0, const float* __restrict__ maskg,
                  float* __restrict__ outg0)
{
    __shared__ short k_lds[BK * KLD];
    __shared__ short vt_lds[HD * VLD];
    __shared__ short p_lds[4 * 16 * PLD];

    const int tid  = threadIdx.x;
    const int wave = tid >> 6;
    const int lane = tid & 63;
    const int quad = lane >> 4;
    const int l16  = lane & 15;

    const int bh = blockIdx.x;
    const int q0 = blockIdx.y * BQ;

    const float* qg   = qg0 + (size_t)bh * S_LEN * HD;
    const float* kg   = kg0 + (size_t)bh * S_LEN * HD;
    const float* vg   = vg0 + (size_t)bh * S_LEN * HD;
    float*       outg = outg0 + (size_t)bh * S_LEN * HD;

    bf16x8 qf[4];
    {
        const float* qrow = qg + (size_t)(q0 + wave * 16 + l16) * HD + quad * 8;
        #pragma unroll
        for (int ks = 0; ks < 4; ++ks) {
            const f32x4 a = *(const f32x4*)(qrow + ks * 32);
            const f32x4 b = *(const f32x4*)(qrow + ks * 32 + 4);
            #pragma unroll
            for (int j = 0; j < 4; ++j) {
                qf[ks][j]     = (short)f2bf(a[j]);
                qf[ks][j + 4] = (short)f2bf(b[j]);
            }
        }
    }

    float m_run[4], l_run[4];
    f32x4 oacc[8];
    #pragma unroll
    for (int r = 0; r < 4; ++r) { m_run[r] = -3.0e38f; l_run[r] = 0.0f; }
    #pragma unroll
    for (int d = 0; d < 8; ++d) oacc[d] = (f32x4){0.f, 0.f, 0.f, 0.f};

    const float scale = 0.088388347648318447f;
    const float* mrow = maskg + (size_t)(q0 + wave * 16 + quad * 4) * S_LEN + l16;

    const int rr = tid >> 5;
    const int cc = tid & 31;
    short* const pw = &p_lds[wave * 16 * PLD];

    f32x4 kpre[8], vpre[8];
    float mpre[4][4];
    #pragma unroll
    for (int it = 0; it < 8; ++it)
        kpre[it] = *(const f32x4*)(kg + (size_t)(rr + 8 * it) * HD + cc * 4);
    #pragma unroll
    for (int it = 0; it < 8; ++it)
        vpre[it] = *(const f32x4*)(vg + (size_t)(rr * 8 + it) * HD + cc * 4);
    #pragma unroll
    for (int nt = 0; nt < 4; ++nt)
        #pragma unroll
        for (int r = 0; r < 4; ++r)
            mpre[nt][r] = mrow[(size_t)r * S_LEN + nt * 16];

    for (int kt = 0; kt < NT; ++kt) {
        __syncthreads();

        #pragma unroll
        for (int it = 0; it < 8; ++it) {
            s16x4 kb4;
            kb4[0] = (short)f2bf(kpre[it][0]); kb4[1] = (short)f2bf(kpre[it][1]);
            kb4[2] = (short)f2bf(kpre[it][2]); kb4[3] = (short)f2bf(kpre[it][3]);
            *(s16x4*)&k_lds[(rr + 8 * it) * KLD + cc * 4] = kb4;
        }
        #pragma unroll
        for (int i = 0; i < 4; ++i) {
            bf16x8 col;
            #pragma unroll
            for (int it = 0; it < 8; ++it)
                col[it] = (short)f2bf(vpre[it][i]);
            const int d = cc * 4 + i;
            const int pblk = rr ^ (cc & 7);
            *(bf16x8*)&vt_lds[d * VLD + pblk * 8] = col;
        }
        __syncthreads();

        const int nb = (kt + 1 < NT) ? (kt + 1) * BK : 0;
        #pragma unroll
        for (int it = 0; it < 8; ++it)
            kpre[it] = *(const f32x4*)(kg + (size_t)(nb + rr + 8 * it) * HD + cc * 4);
        #pragma unroll
        for (int it = 0; it < 8; ++it)
            vpre[it] = *(const f32x4*)(vg + (size_t)(nb + rr * 8 + it) * HD + cc * 4);

        f32x4 sf[4];
        #pragma unroll
        for (int nt = 0; nt < 4; ++nt) {
            f32x4 acc = (f32x4){0.f, 0.f, 0.f, 0.f};
            #pragma unroll
            for (int ks = 0; ks < 4; ++ks) {
                const bf16x8 kf =
                    *(const bf16x8*)&k_lds[(nt * 16 + l16) * KLD + ks * 32 + quad * 8];
                acc = __builtin_amdgcn_mfma_f32_16x16x32_bf16(qf[ks], kf, acc, 0, 0, 0);
            }
            sf[nt] = acc;
        }

        float sv[4][4];
        float mx[4] = {-3.0e38f, -3.0e38f, -3.0e38f, -3.0e38f};
        #pragma unroll
        for (int nt = 0; nt < 4; ++nt)
            #pragma unroll
            for (int r = 0; r < 4; ++r) {
                const float s = sf[nt][r] * scale + mpre[nt][r];
                sv[nt][r] = s;
                mx[r] = fmaxf(mx[r], s);
            }

        #pragma unroll
        for (int nt = 0; nt < 4; ++nt)
            #pragma unroll
            for (int r = 0; r < 4; ++r)
                mpre[nt][r] = mrow[(size_t)r * S_LEN + nb + nt * 16];

        #pragma unroll
        for (int r = 0; r < 4; ++r) {
            mx[r] = fmaxf(mx[r], __shfl_xor(mx[r], 1, 16));
            mx[r] = fmaxf(mx[r], __shfl_xor(mx[r], 2, 16));
            mx[r] = fmaxf(mx[r], __shfl_xor(mx[r], 4, 16));
            mx[r] = fmaxf(mx[r], __shfl_xor(mx[r], 8, 16));
        }

        float alpha[4], pl[4];
        #pragma unroll
        for (int r = 0; r < 4; ++r) {
            const float mnew = fmaxf(m_run[r], mx[r]);
            alpha[r] = __expf(m_run[r] - mnew);
            m_run[r] = mnew;
            pl[r] = 0.f;
        }

        short pb[4][4];
        #pragma unroll
        for (int nt = 0; nt < 4; ++nt)
            #pragma unroll
            for (int r = 0; r < 4; ++r) {
                const float p = __expf(sv[nt][r] - m_run[r]);
                const unsigned short b = f2bf(p);
                pb[nt][r] = (short)b;
                pl[r] += __builtin_bit_cast(float, (unsigned int)b << 16);
            }
        #pragma unroll
        for (int r = 0; r < 4; ++r) {
            pl[r] += __shfl_xor(pl[r], 1, 16);
            pl[r] += __shfl_xor(pl[r], 2, 16);
            pl[r] += __shfl_xor(pl[r], 4, 16);
            pl[r] += __shfl_xor(pl[r], 8, 16);
            l_run[r] = l_run[r] * alpha[r] + pl[r];
        }
        #pragma unroll
        for (int d = 0; d < 8; ++d)
            #pragma unroll
            for (int r = 0; r < 4; ++r)
                oacc[d][r] *= alpha[r];

        #pragma unroll
        for (int nt = 0; nt < 4; ++nt)
            #pragma unroll
            for (int r = 0; r < 4; ++r)
                pw[(quad * 4 + r) * PLD + nt * 16 + l16] = pb[nt][r];

        bf16x8 pf[2];
        #pragma unroll
        for (int ks = 0; ks < 2; ++ks) {
            const s16x4 lo = *(const s16x4*)&pw[l16 * PLD + ks * 32 + quad * 8];
            const s16x4 hi = *(const s16x4*)&pw[l16 * PLD + ks * 32 + quad * 8 + 4];
            pf[ks] = __builtin_shufflevector(lo, hi, 0, 1, 2, 3, 4, 5, 6, 7);
        }

        #pragma unroll
        for (int dt = 0; dt < 8; ++dt) {
            const int drow = dt * 16 + l16;
            const int tsw  = (drow >> 2) & 7;
            #pragma unroll
            for (int ks = 0; ks < 2; ++ks) {
                const bf16x8 vf =
                    *(const bf16x8*)&vt_lds[drow * VLD + (((4 * ks + quad) ^ tsw) * 8)];
                oacc[dt] = __builtin_amdgcn_mfma_f32_16x16x32_bf16(pf[ks], vf, oacc[dt], 0, 0, 0);
            }
        }
    }

    const int orow0 = q0 + wave * 16 + quad * 4;
    #pragma unroll
    for (int r = 0; r < 4; ++r) {
        const float inv = 1.0f / l_run[r];
        float* orow = outg + (size_t)(orow0 + r) * HD + l16;
        #pragma unroll
        for (int d = 0; d < 8; ++d)
            orow[d * 16] = oacc[d][r] * inv;
    }
}

extern "C" void kernel_launch(void* const* d_in, const int* in_sizes, int n_in,
                              void* d_out, int out_size, void* d_ws, size_t ws_size,
                              hipStream_t stream) {
    const float* q    = (const float*)d_in[0];
    const float* k    = (const float*)d_in[1];
    const float* v    = (const float*)d_in[2];
    const float* mask = (const float*)d_in[3];
    float* out = (float*)d_out;

    const size_t need = (size_t)2 * NBH * NT * TILE_SH * sizeof(short); // 64 MB
    dim3 grid(NBH, S_LEN / BQ);
    if (d_ws != nullptr && ws_size >= need) {
        short* wsk = (short*)d_ws;
        short* wsv = wsk + (size_t)NBH * NT * TILE_SH;
        dim3 pgrid(NT, NBH, 2);
        prep_kernel<<<pgrid, 256, 0, stream>>>(k, v, wsk, wsv);
        fattn_ws_kernel<<<grid, 256, 0, stream>>>(wsk, wsv, q, mask, out);
    } else {
        fattn_legacy<<<grid, 256, 0, stream>>>(q, k, v, mask, out);
    }
}

// Round 4
// 531.464 us; speedup vs baseline: 1.0981x; 1.0687x over previous
//
#include <hip/hip_runtime.h>

// Flash-attention fwd, B=4 H=16 S=2048 D=128, fp32 in/out, bf16 MFMA compute.
// Round 6: occupancy. Round-5 proved the prepass/global_load_lds staging path
// numerically exact (absmax 0.0078, main 414 us) but latency-bound at
// 2 blocks/CU. This round drops the dedicated P-exchange LDS: during the P
// exchange in iter kt, k_lds[(kt+1)&1] holds dead data (K[kt+1]'s DMA is
// issued only after the 2nd barrier, P reads finish before it), so the P
// exchange reuses that buffer. LDS 57856 -> 49152 B => 3 blocks/CU.
// Numerics bit-identical to the passing round-5 kernel.

#define S_LEN 2048
#define HD 128
#define BQ 64
#define BK 64
#define NT (S_LEN / BK)          // 32
#define TILE_SH (BK * HD)        // 8192 shorts = 16 KB per staged tile image
#define PLD 68                   // P scratch row stride -> conflict-free
#define NBH 64

typedef __attribute__((ext_vector_type(8))) short bf16x8;
typedef __attribute__((ext_vector_type(4))) float f32x4;
typedef __attribute__((ext_vector_type(4))) short s16x4;

static __device__ __forceinline__ unsigned short f2bf(float f) {
    unsigned int u = __builtin_bit_cast(unsigned int, f);
    u += 0x7fffu + ((u >> 16) & 1u);   // round-to-nearest-even
    return (unsigned short)(u >> 16);
}

// global -> LDS direct DMA, 16B per lane; LDS dest = wave-uniform base + lane*16
static __device__ __forceinline__ void gload16(const short* g, short* l) {
    __builtin_amdgcn_global_load_lds(
        (const __attribute__((address_space(1))) unsigned int*)(const void*)g,
        (__attribute__((address_space(3))) unsigned int*)(void*)l,
        16, 0, 0);
}

// ---------------------------------------------------------------------------
// Prepass: build bf16 tile images in workspace (unchanged from round 5).
//   K image [bh][kt][row 0..63][cb 0..15][8]: phys block cb holds logical
//     block cb^(row&7) of K[row] (8 bf16 each).
//   V image [bh][kt][d 0..127][cb 0..7][8]: phys block cb holds
//     V[kt*64 + ((cb^(d&7))*8) .. +8][d].
// ---------------------------------------------------------------------------
__global__ __launch_bounds__(256)
void prep_kernel(const float* __restrict__ kg0, const float* __restrict__ vg0,
                 short* __restrict__ wsk, short* __restrict__ wsv)
{
    const int kt = blockIdx.x;
    const int bh = blockIdx.y;
    const int t  = threadIdx.x;
    if (blockIdx.z == 0) {
        const float* src = kg0 + ((size_t)bh * S_LEN + kt * BK) * HD;
        short* dst = wsk + ((size_t)bh * NT + kt) * TILE_SH;
        #pragma unroll
        for (int i = 0; i < 4; ++i) {
            const int c = t + 256 * i;
            const int row = c >> 4, cb = c & 15;
            const float* s = src + row * HD + ((cb ^ (row & 7)) << 3);
            const f32x4 a = *(const f32x4*)s;
            const f32x4 b = *(const f32x4*)(s + 4);
            bf16x8 o;
            #pragma unroll
            for (int j = 0; j < 4; ++j) {
                o[j]     = (short)f2bf(a[j]);
                o[j + 4] = (short)f2bf(b[j]);
            }
            *(bf16x8*)(dst + (size_t)c * 8) = o;
        }
    } else {
        __shared__ short lv[BK * 136];    // [kk][d] staging for the transpose
        const float* src = vg0 + ((size_t)bh * S_LEN + kt * BK) * HD;
        short* dst = wsv + ((size_t)bh * NT + kt) * TILE_SH;
        #pragma unroll
        for (int p = 0; p < 2; ++p) {
            const int kk = (t >> 3) + p * 32;
            const int d0 = (t & 7) * 16;
            const float* s = src + kk * HD + d0;
            #pragma unroll
            for (int g = 0; g < 2; ++g) {
                const f32x4 a = *(const f32x4*)(s + g * 8);
                const f32x4 b = *(const f32x4*)(s + g * 8 + 4);
                bf16x8 o;
                #pragma unroll
                for (int j = 0; j < 4; ++j) {
                    o[j]     = (short)f2bf(a[j]);
                    o[j + 4] = (short)f2bf(b[j]);
                }
                *(bf16x8*)&lv[kk * 136 + d0 + g * 8] = o;
            }
        }
        __syncthreads();
        #pragma unroll
        for (int i = 0; i < 4; ++i) {
            const int c = t + 256 * i;
            const int d = c >> 3, cb = c & 7;
            const int kk0 = (cb ^ (d & 7)) << 3;
            bf16x8 o;
            #pragma unroll
            for (int j = 0; j < 8; ++j) o[j] = lv[(kk0 + j) * 136 + d];
            *(bf16x8*)(dst + (size_t)c * 8) = o;
        }
    }
}

// ---------------------------------------------------------------------------
// Main kernel: 48 KB LDS => 3 blocks/CU.
// ---------------------------------------------------------------------------
__global__ __launch_bounds__(256, 3)
void fattn_ws_kernel(const short* __restrict__ wsk, const short* __restrict__ wsv,
                     const float* __restrict__ qg0, const float* __restrict__ maskg,
                     float* __restrict__ outg0)
{
    // k_lds double-buffers the K tile image; the idle half also serves as the
    // per-wave P-exchange scratch (dead between 2nd barrier of iter kt-1 and
    // the K[kt+1] DMA issued after the 2nd barrier of iter kt).
    __shared__ short k_lds[2][TILE_SH];
    __shared__ short v_lds[TILE_SH];      // single-buffered V^T tile image

    const int tid  = threadIdx.x;
    const int wave = tid >> 6;
    const int lane = tid & 63;
    const int quad = lane >> 4;
    const int l16  = lane & 15;

    const int bh = blockIdx.x;            // fast dim: co-resident blocks share K/V
    const int q0 = blockIdx.y * BQ;

    const float* qg   = qg0 + (size_t)bh * S_LEN * HD;
    float*       outg = outg0 + (size_t)bh * S_LEN * HD;
    const short* ktiles = wsk + (size_t)bh * NT * TILE_SH;
    const short* vtiles = wsv + (size_t)bh * NT * TILE_SH;

    const int soff = tid * 8;             // per-thread offset in tile (shorts)
    const int loff = (tid & ~63) * 8;     // wave-uniform LDS offset (shorts)

    // issue K tile 0 immediately (drained by first barrier)
    #pragma unroll
    for (int p = 0; p < 4; ++p)
        gload16(ktiles + p * 2048 + soff, &k_lds[0][p * 2048 + loff]);

    // Q A-fragments: m = l16, k = ks*32 + quad*8 + j  (held for whole kernel)
    bf16x8 qf[4];
    {
        const float* qrow = qg + (size_t)(q0 + wave * 16 + l16) * HD + quad * 8;
        #pragma unroll
        for (int ks = 0; ks < 4; ++ks) {
            const f32x4 a = *(const f32x4*)(qrow + ks * 32);
            const f32x4 b = *(const f32x4*)(qrow + ks * 32 + 4);
            #pragma unroll
            for (int j = 0; j < 4; ++j) {
                qf[ks][j]     = (short)f2bf(a[j]);
                qf[ks][j + 4] = (short)f2bf(b[j]);
            }
        }
    }

    float m_run[4], l_run[4];
    f32x4 oacc[8];
    #pragma unroll
    for (int r = 0; r < 4; ++r) { m_run[r] = -3.0e38f; l_run[r] = 0.0f; }
    #pragma unroll
    for (int d = 0; d < 8; ++d) oacc[d] = (f32x4){0.f, 0.f, 0.f, 0.f};

    const float scale = 0.088388347648318447f;  // 1/sqrt(128)
    const float* mrow = maskg + (size_t)(q0 + wave * 16 + quad * 4) * S_LEN + l16;

    float mpre[4][4];
    #pragma unroll
    for (int nt = 0; nt < 4; ++nt)
        #pragma unroll
        for (int r = 0; r < 4; ++r)
            mpre[nt][r] = mrow[(size_t)r * S_LEN + nt * 16];

    // LDS fragment-read bases (shorts). Swizzled block index decomposes into
    // base ^ (ks-bit) + immediates -> zero per-iteration address VALU.
    const int kb0 = l16 * 128 + ((quad ^ (l16 & 3)) << 3) + (((l16 >> 2) & 1) << 5);
    const int kb1 = kb0 ^ 32;
    const int vb0 = l16 * 64  + ((quad ^ (l16 & 3)) << 3) + (((l16 >> 2) & 1) << 5);
    const int vb1 = vb0 ^ 32;

    for (int kt = 0; kt < NT; ++kt) {
        const short* kcur = k_lds[kt & 1];
        // P-exchange scratch lives in the *other* K buffer (dead this phase).
        short* const pw = &k_lds[(kt + 1) & 1][wave * 16 * PLD];

        asm volatile("s_waitcnt vmcnt(0)" ::: "memory");  // K[kt] DMA landed
        __syncthreads();

        // issue V[kt]; latency hidden under QK^T + softmax
        #pragma unroll
        for (int p = 0; p < 4; ++p)
            gload16(vtiles + (size_t)kt * TILE_SH + p * 2048 + soff,
                    &v_lds[p * 2048 + loff]);

        // ---- S = Q K^T ----
        f32x4 sf[4];
        #pragma unroll
        for (int nt = 0; nt < 4; ++nt) {
            f32x4 acc = (f32x4){0.f, 0.f, 0.f, 0.f};
            #pragma unroll
            for (int ks = 0; ks < 4; ++ks) {
                const bf16x8 kf = *(const bf16x8*)
                    &kcur[((ks & 1) ? kb1 : kb0) + (ks >> 1) * 64 + nt * 2048];
                acc = __builtin_amdgcn_mfma_f32_16x16x32_bf16(qf[ks], kf, acc, 0, 0, 0);
            }
            sf[nt] = acc;
        }

        float sv[4][4];
        float mx[4] = {-3.0e38f, -3.0e38f, -3.0e38f, -3.0e38f};
        #pragma unroll
        for (int nt = 0; nt < 4; ++nt)
            #pragma unroll
            for (int r = 0; r < 4; ++r) {
                const float s = sf[nt][r] * scale + mpre[nt][r];
                sv[nt][r] = s;
                mx[r] = fmaxf(mx[r], s);
            }

        #pragma unroll
        for (int r = 0; r < 4; ++r) {
            mx[r] = fmaxf(mx[r], __shfl_xor(mx[r], 1, 16));
            mx[r] = fmaxf(mx[r], __shfl_xor(mx[r], 2, 16));
            mx[r] = fmaxf(mx[r], __shfl_xor(mx[r], 4, 16));
            mx[r] = fmaxf(mx[r], __shfl_xor(mx[r], 8, 16));
        }

        float alpha[4], pl[4];
        #pragma unroll
        for (int r = 0; r < 4; ++r) {
            const float mnew = fmaxf(m_run[r], mx[r]);
            alpha[r] = __expf(m_run[r] - mnew);
            m_run[r] = mnew;
            pl[r] = 0.f;
        }

        short pb[4][4];
        #pragma unroll
        for (int nt = 0; nt < 4; ++nt)
            #pragma unroll
            for (int r = 0; r < 4; ++r) {
                const float p = __expf(sv[nt][r] - m_run[r]);
                const unsigned short b = f2bf(p);
                pb[nt][r] = (short)b;
                // accumulate l from the *rounded* p so normalization matches PV
                pl[r] += __builtin_bit_cast(float, (unsigned int)b << 16);
            }
        #pragma unroll
        for (int r = 0; r < 4; ++r) {
            pl[r] += __shfl_xor(pl[r], 1, 16);
            pl[r] += __shfl_xor(pl[r], 2, 16);
            pl[r] += __shfl_xor(pl[r], 4, 16);
            pl[r] += __shfl_xor(pl[r], 8, 16);
            l_run[r] = l_run[r] * alpha[r] + pl[r];
        }
        #pragma unroll
        for (int d = 0; d < 8; ++d)
            #pragma unroll
            for (int r = 0; r < 4; ++r)
                oacc[d][r] *= alpha[r];

        // ---- P: C-layout -> scratch LDS -> A-layout (per-wave, no barrier) ----
        #pragma unroll
        for (int nt = 0; nt < 4; ++nt)
            #pragma unroll
            for (int r = 0; r < 4; ++r)
                pw[(quad * 4 + r) * PLD + nt * 16 + l16] = pb[nt][r];

        bf16x8 pf[2];
        #pragma unroll
        for (int ks = 0; ks < 2; ++ks) {
            const s16x4 lo = *(const s16x4*)&pw[l16 * PLD + ks * 32 + quad * 8];
            const s16x4 hi = *(const s16x4*)&pw[l16 * PLD + ks * 32 + quad * 8 + 4];
            pf[ks] = __builtin_shufflevector(lo, hi, 0, 1, 2, 3, 4, 5, 6, 7);
        }

        asm volatile("s_waitcnt vmcnt(0)" ::: "memory");  // V[kt] DMA landed
        __syncthreads();

        // issue K[kt+1] (overwrites the P scratch -- reads completed above)
        const int nk = (kt + 1) & (NT - 1);
        #pragma unroll
        for (int p = 0; p < 4; ++p)
            gload16(ktiles + (size_t)nk * TILE_SH + p * 2048 + soff,
                    &k_lds[nk & 1][p * 2048 + loff]);
        const int nb = nk * BK;
        #pragma unroll
        for (int nt = 0; nt < 4; ++nt)
            #pragma unroll
            for (int r = 0; r < 4; ++r)
                mpre[nt][r] = mrow[(size_t)r * S_LEN + nb + nt * 16];

        // ---- O += P V ----
        #pragma unroll
        for (int dt = 0; dt < 8; ++dt) {
            #pragma unroll
            for (int ks = 0; ks < 2; ++ks) {
                const bf16x8 vf = *(const bf16x8*)&v_lds[(ks ? vb1 : vb0) + dt * 1024];
                oacc[dt] = __builtin_amdgcn_mfma_f32_16x16x32_bf16(pf[ks], vf, oacc[dt], 0, 0, 0);
            }
        }
    }

    // ---- epilogue: normalize and store ----
    const int orow0 = q0 + wave * 16 + quad * 4;
    #pragma unroll
    for (int r = 0; r < 4; ++r) {
        const float inv = 1.0f / l_run[r];
        float* orow = outg + (size_t)(orow0 + r) * HD + l16;
        #pragma unroll
        for (int d = 0; d < 8; ++d)
            orow[d * 16] = oacc[d][r] * inv;
    }
}

// ---------------------------------------------------------------------------
// Legacy kernel (round 3, proven) — fallback if workspace is too small.
// ---------------------------------------------------------------------------
#define KLD 136
#define VLD 72

__global__ __launch_bounds__(256, 2)
void fattn_legacy(const float* __restrict__ qg0, const float* __restrict__ kg0,
                  const float* __restrict__ vg0, const float* __restrict__ maskg,
                  float* __restrict__ outg0)
{
    __shared__ short k_lds[BK * KLD];
    __shared__ short vt_lds[HD * VLD];
    __shared__ short p_lds[4 * 16 * PLD];

    const int tid  = threadIdx.x;
    const int wave = tid >> 6;
    const int lane = tid & 63;
    const int quad = lane >> 4;
    const int l16  = lane & 15;

    const int bh = blockIdx.x;
    const int q0 = blockIdx.y * BQ;

    const float* qg   = qg0 + (size_t)bh * S_LEN * HD;
    const float* kg   = kg0 + (size_t)bh * S_LEN * HD;
    const float* vg   = vg0 + (size_t)bh * S_LEN * HD;
    float*       outg = outg0 + (size_t)bh * S_LEN * HD;

    bf16x8 qf[4];
    {
        const float* qrow = qg + (size_t)(q0 + wave * 16 + l16) * HD + quad * 8;
        #pragma unroll
        for (int ks = 0; ks < 4; ++ks) {
            const f32x4 a = *(const f32x4*)(qrow + ks * 32);
            const f32x4 b = *(const f32x4*)(qrow + ks * 32 + 4);
            #pragma unroll
            for (int j = 0; j < 4; ++j) {
                qf[ks][j]     = (short)f2bf(a[j]);
                qf[ks][j + 4] = (short)f2bf(b[j]);
            }
        }
    }

    float m_run[4], l_run[4];
    f32x4 oacc[8];
    #pragma unroll
    for (int r = 0; r < 4; ++r) { m_run[r] = -3.0e38f; l_run[r] = 0.0f; }
    #pragma unroll
    for (int d = 0; d < 8; ++d) oacc[d] = (f32x4){0.f, 0.f, 0.f, 0.f};

    const float scale = 0.088388347648318447f;
    const float* mrow = maskg + (size_t)(q0 + wave * 16 + quad * 4) * S_LEN + l16;

    const int rr = tid >> 5;
    const int cc = tid & 31;
    short* const pw = &p_lds[wave * 16 * PLD];

    f32x4 kpre[8], vpre[8];
    float mpre[4][4];
    #pragma unroll
    for (int it = 0; it < 8; ++it)
        kpre[it] = *(const f32x4*)(kg + (size_t)(rr + 8 * it) * HD + cc * 4);
    #pragma unroll
    for (int it = 0; it < 8; ++it)
        vpre[it] = *(const f32x4*)(vg + (size_t)(rr * 8 + it) * HD + cc * 4);
    #pragma unroll
    for (int nt = 0; nt < 4; ++nt)
        #pragma unroll
        for (int r = 0; r < 4; ++r)
            mpre[nt][r] = mrow[(size_t)r * S_LEN + nt * 16];

    for (int kt = 0; kt < NT; ++kt) {
        __syncthreads();

        #pragma unroll
        for (int it = 0; it < 8; ++it) {
            s16x4 kb4;
            kb4[0] = (short)f2bf(kpre[it][0]); kb4[1] = (short)f2bf(kpre[it][1]);
            kb4[2] = (short)f2bf(kpre[it][2]); kb4[3] = (short)f2bf(kpre[it][3]);
            *(s16x4*)&k_lds[(rr + 8 * it) * KLD + cc * 4] = kb4;
        }
        #pragma unroll
        for (int i = 0; i < 4; ++i) {
            bf16x8 col;
            #pragma unroll
            for (int it = 0; it < 8; ++it)
                col[it] = (short)f2bf(vpre[it][i]);
            const int d = cc * 4 + i;
            const int pblk = rr ^ (cc & 7);
            *(bf16x8*)&vt_lds[d * VLD + pblk * 8] = col;
        }
        __syncthreads();

        const int nb = (kt + 1 < NT) ? (kt + 1) * BK : 0;
        #pragma unroll
        for (int it = 0; it < 8; ++it)
            kpre[it] = *(const f32x4*)(kg + (size_t)(nb + rr + 8 * it) * HD + cc * 4);
        #pragma unroll
        for (int it = 0; it < 8; ++it)
            vpre[it] = *(const f32x4*)(vg + (size_t)(nb + rr * 8 + it) * HD + cc * 4);

        f32x4 sf[4];
        #pragma unroll
        for (int nt = 0; nt < 4; ++nt) {
            f32x4 acc = (f32x4){0.f, 0.f, 0.f, 0.f};
            #pragma unroll
            for (int ks = 0; ks < 4; ++ks) {
                const bf16x8 kf =
                    *(const bf16x8*)&k_lds[(nt * 16 + l16) * KLD + ks * 32 + quad * 8];
                acc = __builtin_amdgcn_mfma_f32_16x16x32_bf16(qf[ks], kf, acc, 0, 0, 0);
            }
            sf[nt] = acc;
        }

        float sv[4][4];
        float mx[4] = {-3.0e38f, -3.0e38f, -3.0e38f, -3.0e38f};
        #pragma unroll
        for (int nt = 0; nt < 4; ++nt)
            #pragma unroll
            for (int r = 0; r < 4; ++r) {
                const float s = sf[nt][r] * scale + mpre[nt][r];
                sv[nt][r] = s;
                mx[r] = fmaxf(mx[r], s);
            }

        #pragma unroll
        for (int nt = 0; nt < 4; ++nt)
            #pragma unroll
            for (int r = 0; r < 4; ++r)
                mpre[nt][r] = mrow[(size_t)r * S_LEN + nb + nt * 16];

        #pragma unroll
        for (int r = 0; r < 4; ++r) {
            mx[r] = fmaxf(mx[r], __shfl_xor(mx[r], 1, 16));
            mx[r] = fmaxf(mx[r], __shfl_xor(mx[r], 2, 16));
            mx[r] = fmaxf(mx[r], __shfl_xor(mx[r], 4, 16));
            mx[r] = fmaxf(mx[r], __shfl_xor(mx[r], 8, 16));
        }

        float alpha[4], pl[4];
        #pragma unroll
        for (int r = 0; r < 4; ++r) {
            const float mnew = fmaxf(m_run[r], mx[r]);
            alpha[r] = __expf(m_run[r] - mnew);
            m_run[r] = mnew;
            pl[r] = 0.f;
        }

        short pb[4][4];
        #pragma unroll
        for (int nt = 0; nt < 4; ++nt)
            #pragma unroll
            for (int r = 0; r < 4; ++r) {
                const float p = __expf(sv[nt][r] - m_run[r]);
                const unsigned short b = f2bf(p);
                pb[nt][r] = (short)b;
                pl[r] += __builtin_bit_cast(float, (unsigned int)b << 16);
            }
        #pragma unroll
        for (int r = 0; r < 4; ++r) {
            pl[r] += __shfl_xor(pl[r], 1, 16);
            pl[r] += __shfl_xor(pl[r], 2, 16);
            pl[r] += __shfl_xor(pl[r], 4, 16);
            pl[r] += __shfl_xor(pl[r], 8, 16);
            l_run[r] = l_run[r] * alpha[r] + pl[r];
        }
        #pragma unroll
        for (int d = 0; d < 8; ++d)
            #pragma unroll
            for (int r = 0; r < 4; ++r)
                oacc[d][r] *= alpha[r];

        #pragma unroll
        for (int nt = 0; nt < 4; ++nt)
            #pragma unroll
            for (int r = 0; r < 4; ++r)
                pw[(quad * 4 + r) * PLD + nt * 16 + l16] = pb[nt][r];

        bf16x8 pf[2];
        #pragma unroll
        for (int ks = 0; ks < 2; ++ks) {
            const s16x4 lo = *(const s16x4*)&pw[l16 * PLD + ks * 32 + quad * 8];
            const s16x4 hi = *(const s16x4*)&pw[l16 * PLD + ks * 32 + quad * 8 + 4];
            pf[ks] = __builtin_shufflevector(lo, hi, 0, 1, 2, 3, 4, 5, 6, 7);
        }

        #pragma unroll
        for (int dt = 0; dt < 8; ++dt) {
            const int drow = dt * 16 + l16;
            const int tsw  = (drow >> 2) & 7;
            #pragma unroll
            for (int ks = 0; ks < 2; ++ks) {
                const bf16x8 vf =
                    *(const bf16x8*)&vt_lds[drow * VLD + (((4 * ks + quad) ^ tsw) * 8)];
                oacc[dt] = __builtin_amdgcn_mfma_f32_16x16x32_bf16(pf[ks], vf, oacc[dt], 0, 0, 0);
            }
        }
    }

    const int orow0 = q0 + wave * 16 + quad * 4;
    #pragma unroll
    for (int r = 0; r < 4; ++r) {
        const float inv = 1.0f / l_run[r];
        float* orow = outg + (size_t)(orow0 + r) * HD + l16;
        #pragma unroll
        for (int d = 0; d < 8; ++d)
            orow[d * 16] = oacc[d][r] * inv;
    }
}

extern "C" void kernel_launch(void* const* d_in, const int* in_sizes, int n_in,
                              void* d_out, int out_size, void* d_ws, size_t ws_size,
                              hipStream_t stream) {
    const float* q    = (const float*)d_in[0];
    const float* k    = (const float*)d_in[1];
    const float* v    = (const float*)d_in[2];
    const float* mask = (const float*)d_in[3];
    float* out = (float*)d_out;

    const size_t need = (size_t)2 * NBH * NT * TILE_SH * sizeof(short); // 64 MB
    dim3 grid(NBH, S_LEN / BQ);
    if (d_ws != nullptr && ws_size >= need) {
        short* wsk = (short*)d_ws;
        short* wsv = wsk + (size_t)NBH * NT * TILE_SH;
        dim3 pgrid(NT, NBH, 2);
        prep_kernel<<<pgrid, 256, 0, stream>>>(k, v, wsk, wsv);
        fattn_ws_kernel<<<grid, 256, 0, stream>>>(wsk, wsv, q, mask, out);
    } else {
        fattn_legacy<<<grid, 256, 0, stream>>>(q, k, v, mask, out);
    }
}

// Round 5
// 515.831 us; speedup vs baseline: 1.1314x; 1.0303x over previous
//
#include <hip/hip_runtime.h>

// Flash-attention fwd, B=4 H=16 S=2048 D=128, fp32 in/out, bf16 MFMA compute.
// Round 7: critical-path VALU. On the round-6 structure (prepass tile images +
// global_load_lds staging, scratch-P in idle K buffer, 3 blocks/CU, explicit
// vmcnt waits): (a) softmax in exp2 domain (scale/mask pre-multiplied by
// log2e), (b) defer-max: skip O-rescale/alpha while the running max grows <8
// (p bounded by 2^8, safe in bf16), (c) s_setprio(1) around MFMA clusters
// (independent blocks per CU -> scheduler can favor MFMA waves).
// cvt_pk packing deliberately NOT re-added (kept as bisect suspect).

#define S_LEN 2048
#define HD 128
#define BQ 64
#define BK 64
#define NT (S_LEN / BK)          // 32
#define TILE_SH (BK * HD)        // 8192 shorts = 16 KB per staged tile image
#define PLD 68                   // P scratch row stride -> conflict-free
#define NBH 64

typedef __attribute__((ext_vector_type(8))) short bf16x8;
typedef __attribute__((ext_vector_type(4))) float f32x4;
typedef __attribute__((ext_vector_type(4))) short s16x4;

static __device__ __forceinline__ unsigned short f2bf(float f) {
    unsigned int u = __builtin_bit_cast(unsigned int, f);
    u += 0x7fffu + ((u >> 16) & 1u);   // round-to-nearest-even
    return (unsigned short)(u >> 16);
}

// global -> LDS direct DMA, 16B per lane; LDS dest = wave-uniform base + lane*16
static __device__ __forceinline__ void gload16(const short* g, short* l) {
    __builtin_amdgcn_global_load_lds(
        (const __attribute__((address_space(1))) unsigned int*)(const void*)g,
        (__attribute__((address_space(3))) unsigned int*)(void*)l,
        16, 0, 0);
}

// ---------------------------------------------------------------------------
// Prepass: build bf16 tile images in workspace (unchanged; ~54 us, near its
// HBM floor).
//   K image [bh][kt][row 0..63][cb 0..15][8]: phys block cb holds logical
//     block cb^(row&7) of K[row] (8 bf16 each).
//   V image [bh][kt][d 0..127][cb 0..7][8]: phys block cb holds
//     V[kt*64 + ((cb^(d&7))*8) .. +8][d].
// ---------------------------------------------------------------------------
__global__ __launch_bounds__(256)
void prep_kernel(const float* __restrict__ kg0, const float* __restrict__ vg0,
                 short* __restrict__ wsk, short* __restrict__ wsv)
{
    const int kt = blockIdx.x;
    const int bh = blockIdx.y;
    const int t  = threadIdx.x;
    if (blockIdx.z == 0) {
        const float* src = kg0 + ((size_t)bh * S_LEN + kt * BK) * HD;
        short* dst = wsk + ((size_t)bh * NT + kt) * TILE_SH;
        #pragma unroll
        for (int i = 0; i < 4; ++i) {
            const int c = t + 256 * i;
            const int row = c >> 4, cb = c & 15;
            const float* s = src + row * HD + ((cb ^ (row & 7)) << 3);
            const f32x4 a = *(const f32x4*)s;
            const f32x4 b = *(const f32x4*)(s + 4);
            bf16x8 o;
            #pragma unroll
            for (int j = 0; j < 4; ++j) {
                o[j]     = (short)f2bf(a[j]);
                o[j + 4] = (short)f2bf(b[j]);
            }
            *(bf16x8*)(dst + (size_t)c * 8) = o;
        }
    } else {
        __shared__ short lv[BK * 136];    // [kk][d] staging for the transpose
        const float* src = vg0 + ((size_t)bh * S_LEN + kt * BK) * HD;
        short* dst = wsv + ((size_t)bh * NT + kt) * TILE_SH;
        #pragma unroll
        for (int p = 0; p < 2; ++p) {
            const int kk = (t >> 3) + p * 32;
            const int d0 = (t & 7) * 16;
            const float* s = src + kk * HD + d0;
            #pragma unroll
            for (int g = 0; g < 2; ++g) {
                const f32x4 a = *(const f32x4*)(s + g * 8);
                const f32x4 b = *(const f32x4*)(s + g * 8 + 4);
                bf16x8 o;
                #pragma unroll
                for (int j = 0; j < 4; ++j) {
                    o[j]     = (short)f2bf(a[j]);
                    o[j + 4] = (short)f2bf(b[j]);
                }
                *(bf16x8*)&lv[kk * 136 + d0 + g * 8] = o;
            }
        }
        __syncthreads();
        #pragma unroll
        for (int i = 0; i < 4; ++i) {
            const int c = t + 256 * i;
            const int d = c >> 3, cb = c & 7;
            const int kk0 = (cb ^ (d & 7)) << 3;
            bf16x8 o;
            #pragma unroll
            for (int j = 0; j < 8; ++j) o[j] = lv[(kk0 + j) * 136 + d];
            *(bf16x8*)(dst + (size_t)c * 8) = o;
        }
    }
}

// ---------------------------------------------------------------------------
// Main kernel: 48 KB LDS => 3 blocks/CU.
// ---------------------------------------------------------------------------
__global__ __launch_bounds__(256, 3)
void fattn_ws_kernel(const short* __restrict__ wsk, const short* __restrict__ wsv,
                     const float* __restrict__ qg0, const float* __restrict__ maskg,
                     float* __restrict__ outg0)
{
    // k_lds double-buffers the K tile image; the idle half also serves as the
    // per-wave P-exchange scratch (dead between 2nd barrier of iter kt-1 and
    // the K[kt+1] DMA issued after the 2nd barrier of iter kt).
    __shared__ short k_lds[2][TILE_SH];
    __shared__ short v_lds[TILE_SH];      // single-buffered V^T tile image

    const int tid  = threadIdx.x;
    const int wave = tid >> 6;
    const int lane = tid & 63;
    const int quad = lane >> 4;
    const int l16  = lane & 15;

    const int bh = blockIdx.x;            // fast dim: co-resident blocks share K/V
    const int q0 = blockIdx.y * BQ;

    const float* qg   = qg0 + (size_t)bh * S_LEN * HD;
    float*       outg = outg0 + (size_t)bh * S_LEN * HD;
    const short* ktiles = wsk + (size_t)bh * NT * TILE_SH;
    const short* vtiles = wsv + (size_t)bh * NT * TILE_SH;

    const int soff = tid * 8;             // per-thread offset in tile (shorts)
    const int loff = (tid & ~63) * 8;     // wave-uniform LDS offset (shorts)

    // issue K tile 0 immediately (drained by first barrier)
    #pragma unroll
    for (int p = 0; p < 4; ++p)
        gload16(ktiles + p * 2048 + soff, &k_lds[0][p * 2048 + loff]);

    // Q A-fragments: m = l16, k = ks*32 + quad*8 + j  (held for whole kernel)
    bf16x8 qf[4];
    {
        const float* qrow = qg + (size_t)(q0 + wave * 16 + l16) * HD + quad * 8;
        #pragma unroll
        for (int ks = 0; ks < 4; ++ks) {
            const f32x4 a = *(const f32x4*)(qrow + ks * 32);
            const f32x4 b = *(const f32x4*)(qrow + ks * 32 + 4);
            #pragma unroll
            for (int j = 0; j < 4; ++j) {
                qf[ks][j]     = (short)f2bf(a[j]);
                qf[ks][j + 4] = (short)f2bf(b[j]);
            }
        }
    }

    float m_run[4], l_run[4];
    f32x4 oacc[8];
    #pragma unroll
    for (int r = 0; r < 4; ++r) { m_run[r] = -3.0e38f; l_run[r] = 0.0f; }
    #pragma unroll
    for (int d = 0; d < 8; ++d) oacc[d] = (f32x4){0.f, 0.f, 0.f, 0.f};

    const float LOG2E  = 1.4426950408889634f;
    const float scale2 = 0.088388347648318447f * LOG2E;  // (1/sqrt(128))*log2e
    const float* mrow = maskg + (size_t)(q0 + wave * 16 + quad * 4) * S_LEN + l16;

    float mpre[4][4];
    #pragma unroll
    for (int nt = 0; nt < 4; ++nt)
        #pragma unroll
        for (int r = 0; r < 4; ++r)
            mpre[nt][r] = mrow[(size_t)r * S_LEN + nt * 16] * LOG2E;

    // LDS fragment-read bases (shorts). Swizzled block index decomposes into
    // base ^ (ks-bit) + immediates -> zero per-iteration address VALU.
    const int kb0 = l16 * 128 + ((quad ^ (l16 & 3)) << 3) + (((l16 >> 2) & 1) << 5);
    const int kb1 = kb0 ^ 32;
    const int vb0 = l16 * 64  + ((quad ^ (l16 & 3)) << 3) + (((l16 >> 2) & 1) << 5);
    const int vb1 = vb0 ^ 32;

    for (int kt = 0; kt < NT; ++kt) {
        const short* kcur = k_lds[kt & 1];
        // P-exchange scratch lives in the *other* K buffer (dead this phase).
        short* const pw = &k_lds[(kt + 1) & 1][wave * 16 * PLD];

        asm volatile("s_waitcnt vmcnt(0)" ::: "memory");  // K[kt] DMA landed
        __syncthreads();

        // issue V[kt]; latency hidden under QK^T + softmax
        #pragma unroll
        for (int p = 0; p < 4; ++p)
            gload16(vtiles + (size_t)kt * TILE_SH + p * 2048 + soff,
                    &v_lds[p * 2048 + loff]);

        // ---- S = Q K^T (log2 domain) ----
        f32x4 sf[4];
        __builtin_amdgcn_s_setprio(1);
        #pragma unroll
        for (int nt = 0; nt < 4; ++nt) {
            f32x4 acc = (f32x4){0.f, 0.f, 0.f, 0.f};
            #pragma unroll
            for (int ks = 0; ks < 4; ++ks) {
                const bf16x8 kf = *(const bf16x8*)
                    &kcur[((ks & 1) ? kb1 : kb0) + (ks >> 1) * 64 + nt * 2048];
                acc = __builtin_amdgcn_mfma_f32_16x16x32_bf16(qf[ks], kf, acc, 0, 0, 0);
            }
            sf[nt] = acc;
        }
        __builtin_amdgcn_s_setprio(0);

        float sv[4][4];
        float mx[4] = {-3.0e38f, -3.0e38f, -3.0e38f, -3.0e38f};
        #pragma unroll
        for (int nt = 0; nt < 4; ++nt)
            #pragma unroll
            for (int r = 0; r < 4; ++r) {
                const float s = sf[nt][r] * scale2 + mpre[nt][r];  // log2 units
                sv[nt][r] = s;
                mx[r] = fmaxf(mx[r], s);
            }

        #pragma unroll
        for (int r = 0; r < 4; ++r) {
            mx[r] = fmaxf(mx[r], __shfl_xor(mx[r], 1, 16));
            mx[r] = fmaxf(mx[r], __shfl_xor(mx[r], 2, 16));
            mx[r] = fmaxf(mx[r], __shfl_xor(mx[r], 4, 16));
            mx[r] = fmaxf(mx[r], __shfl_xor(mx[r], 8, 16));
        }

        // ---- defer-max: rescale only when max materially grows (p <= 2^8) ----
        const bool needl = (mx[0] > m_run[0] + 8.0f) | (mx[1] > m_run[1] + 8.0f) |
                           (mx[2] > m_run[2] + 8.0f) | (mx[3] > m_run[3] + 8.0f);
        const int upd = __any((int)needl);
        float alpha[4];
        if (upd) {
            #pragma unroll
            for (int r = 0; r < 4; ++r) {
                const float mnew = fmaxf(m_run[r], mx[r]);
                alpha[r] = __builtin_amdgcn_exp2f(m_run[r] - mnew);
                m_run[r] = mnew;
            }
        }

        // ---- P = exp2(S - m) -> bf16 (rounded l matches PV) ----
        float pl[4] = {0.f, 0.f, 0.f, 0.f};
        short pb[4][4];
        #pragma unroll
        for (int nt = 0; nt < 4; ++nt)
            #pragma unroll
            for (int r = 0; r < 4; ++r) {
                const float p = __builtin_amdgcn_exp2f(sv[nt][r] - m_run[r]);
                const unsigned short b = f2bf(p);
                pb[nt][r] = (short)b;
                pl[r] += __builtin_bit_cast(float, (unsigned int)b << 16);
            }
        #pragma unroll
        for (int r = 0; r < 4; ++r) {
            pl[r] += __shfl_xor(pl[r], 1, 16);
            pl[r] += __shfl_xor(pl[r], 2, 16);
            pl[r] += __shfl_xor(pl[r], 4, 16);
            pl[r] += __shfl_xor(pl[r], 8, 16);
        }
        if (upd) {
            #pragma unroll
            for (int r = 0; r < 4; ++r) l_run[r] = l_run[r] * alpha[r] + pl[r];
            #pragma unroll
            for (int d = 0; d < 8; ++d)
                #pragma unroll
                for (int r = 0; r < 4; ++r) oacc[d][r] *= alpha[r];
        } else {
            #pragma unroll
            for (int r = 0; r < 4; ++r) l_run[r] += pl[r];
        }

        // ---- P: C-layout -> scratch LDS -> A-layout (per-wave, no barrier) ----
        #pragma unroll
        for (int nt = 0; nt < 4; ++nt)
            #pragma unroll
            for (int r = 0; r < 4; ++r)
                pw[(quad * 4 + r) * PLD + nt * 16 + l16] = pb[nt][r];

        bf16x8 pf[2];
        #pragma unroll
        for (int ks = 0; ks < 2; ++ks) {
            const s16x4 lo = *(const s16x4*)&pw[l16 * PLD + ks * 32 + quad * 8];
            const s16x4 hi = *(const s16x4*)&pw[l16 * PLD + ks * 32 + quad * 8 + 4];
            pf[ks] = __builtin_shufflevector(lo, hi, 0, 1, 2, 3, 4, 5, 6, 7);
        }

        asm volatile("s_waitcnt vmcnt(0)" ::: "memory");  // V[kt] DMA landed
        __syncthreads();

        // issue K[kt+1] (overwrites the P scratch -- reads completed above)
        const int nk = (kt + 1) & (NT - 1);
        #pragma unroll
        for (int p = 0; p < 4; ++p)
            gload16(ktiles + (size_t)nk * TILE_SH + p * 2048 + soff,
                    &k_lds[nk & 1][p * 2048 + loff]);
        const int nb = nk * BK;
        #pragma unroll
        for (int nt = 0; nt < 4; ++nt)
            #pragma unroll
            for (int r = 0; r < 4; ++r)
                mpre[nt][r] = mrow[(size_t)r * S_LEN + nb + nt * 16] * LOG2E;

        // ---- O += P V ----
        __builtin_amdgcn_s_setprio(1);
        #pragma unroll
        for (int dt = 0; dt < 8; ++dt) {
            #pragma unroll
            for (int ks = 0; ks < 2; ++ks) {
                const bf16x8 vf = *(const bf16x8*)&v_lds[(ks ? vb1 : vb0) + dt * 1024];
                oacc[dt] = __builtin_amdgcn_mfma_f32_16x16x32_bf16(pf[ks], vf, oacc[dt], 0, 0, 0);
            }
        }
        __builtin_amdgcn_s_setprio(0);
    }

    // ---- epilogue: normalize and store ----
    const int orow0 = q0 + wave * 16 + quad * 4;
    #pragma unroll
    for (int r = 0; r < 4; ++r) {
        const float inv = 1.0f / l_run[r];
        float* orow = outg + (size_t)(orow0 + r) * HD + l16;
        #pragma unroll
        for (int d = 0; d < 8; ++d)
            orow[d * 16] = oacc[d][r] * inv;
    }
}

// ---------------------------------------------------------------------------
// Legacy kernel (round 3, proven) — fallback if workspace is too small.
// ---------------------------------------------------------------------------
#define KLD 136
#define VLD 72

__global__ __launch_bounds__(256, 2)
void fattn_legacy(const float* __restrict__ qg0, const float* __restrict__ kg0,
                  const float* __restrict__ vg0, const float* __restrict__ maskg,
                  float* __restrict__ outg0)
{
    __shared__ short k_lds[BK * KLD];
    __shared__ short vt_lds[HD * VLD];
    __shared__ short p_lds[4 * 16 * PLD];

    const int tid  = threadIdx.x;
    const int wave = tid >> 6;
    const int lane = tid & 63;
    const int quad = lane >> 4;
    const int l16  = lane & 15;

    const int bh = blockIdx.x;
    const int q0 = blockIdx.y * BQ;

    const float* qg   = qg0 + (size_t)bh * S_LEN * HD;
    const float* kg   = kg0 + (size_t)bh * S_LEN * HD;
    const float* vg   = vg0 + (size_t)bh * S_LEN * HD;
    float*       outg = outg0 + (size_t)bh * S_LEN * HD;

    bf16x8 qf[4];
    {
        const float* qrow = qg + (size_t)(q0 + wave * 16 + l16) * HD + quad * 8;
        #pragma unroll
        for (int ks = 0; ks < 4; ++ks) {
            const f32x4 a = *(const f32x4*)(qrow + ks * 32);
            const f32x4 b = *(const f32x4*)(qrow + ks * 32 + 4);
            #pragma unroll
            for (int j = 0; j < 4; ++j) {
                qf[ks][j]     = (short)f2bf(a[j]);
                qf[ks][j + 4] = (short)f2bf(b[j]);
            }
        }
    }

    float m_run[4], l_run[4];
    f32x4 oacc[8];
    #pragma unroll
    for (int r = 0; r < 4; ++r) { m_run[r] = -3.0e38f; l_run[r] = 0.0f; }
    #pragma unroll
    for (int d = 0; d < 8; ++d) oacc[d] = (f32x4){0.f, 0.f, 0.f, 0.f};

    const float scale = 0.088388347648318447f;
    const float* mrow = maskg + (size_t)(q0 + wave * 16 + quad * 4) * S_LEN + l16;

    const int rr = tid >> 5;
    const int cc = tid & 31;
    short* const pw = &p_lds[wave * 16 * PLD];

    f32x4 kpre[8], vpre[8];
    float mpre[4][4];
    #pragma unroll
    for (int it = 0; it < 8; ++it)
        kpre[it] = *(const f32x4*)(kg + (size_t)(rr + 8 * it) * HD + cc * 4);
    #pragma unroll
    for (int it = 0; it < 8; ++it)
        vpre[it] = *(const f32x4*)(vg + (size_t)(rr * 8 + it) * HD + cc * 4);
    #pragma unroll
    for (int nt = 0; nt < 4; ++nt)
        #pragma unroll
        for (int r = 0; r < 4; ++r)
            mpre[nt][r] = mrow[(size_t)r * S_LEN + nt * 16];

    for (int kt = 0; kt < NT; ++kt) {
        __syncthreads();

        #pragma unroll
        for (int it = 0; it < 8; ++it) {
            s16x4 kb4;
            kb4[0] = (short)f2bf(kpre[it][0]); kb4[1] = (short)f2bf(kpre[it][1]);
            kb4[2] = (short)f2bf(kpre[it][2]); kb4[3] = (short)f2bf(kpre[it][3]);
            *(s16x4*)&k_lds[(rr + 8 * it) * KLD + cc * 4] = kb4;
        }
        #pragma unroll
        for (int i = 0; i < 4; ++i) {
            bf16x8 col;
            #pragma unroll
            for (int it = 0; it < 8; ++it)
                col[it] = (short)f2bf(vpre[it][i]);
            const int d = cc * 4 + i;
            const int pblk = rr ^ (cc & 7);
            *(bf16x8*)&vt_lds[d * VLD + pblk * 8] = col;
        }
        __syncthreads();

        const int nb = (kt + 1 < NT) ? (kt + 1) * BK : 0;
        #pragma unroll
        for (int it = 0; it < 8; ++it)
            kpre[it] = *(const f32x4*)(kg + (size_t)(nb + rr + 8 * it) * HD + cc * 4);
        #pragma unroll
        for (int it = 0; it < 8; ++it)
            vpre[it] = *(const f32x4*)(vg + (size_t)(nb + rr * 8 + it) * HD + cc * 4);

        f32x4 sf[4];
        #pragma unroll
        for (int nt = 0; nt < 4; ++nt) {
            f32x4 acc = (f32x4){0.f, 0.f, 0.f, 0.f};
            #pragma unroll
            for (int ks = 0; ks < 4; ++ks) {
                const bf16x8 kf =
                    *(const bf16x8*)&k_lds[(nt * 16 + l16) * KLD + ks * 32 + quad * 8];
                acc = __builtin_amdgcn_mfma_f32_16x16x32_bf16(qf[ks], kf, acc, 0, 0, 0);
            }
            sf[nt] = acc;
        }

        float sv[4][4];
        float mx[4] = {-3.0e38f, -3.0e38f, -3.0e38f, -3.0e38f};
        #pragma unroll
        for (int nt = 0; nt < 4; ++nt)
            #pragma unroll
            for (int r = 0; r < 4; ++r) {
                const float s = sf[nt][r] * scale + mpre[nt][r];
                sv[nt][r] = s;
                mx[r] = fmaxf(mx[r], s);
            }

        #pragma unroll
        for (int nt = 0; nt < 4; ++nt)
            #pragma unroll
            for (int r = 0; r < 4; ++r)
                mpre[nt][r] = mrow[(size_t)r * S_LEN + nb + nt * 16];

        #pragma unroll
        for (int r = 0; r < 4; ++r) {
            mx[r] = fmaxf(mx[r], __shfl_xor(mx[r], 1, 16));
            mx[r] = fmaxf(mx[r], __shfl_xor(mx[r], 2, 16));
            mx[r] = fmaxf(mx[r], __shfl_xor(mx[r], 4, 16));
            mx[r] = fmaxf(mx[r], __shfl_xor(mx[r], 8, 16));
        }

        float alpha[4], pl[4];
        #pragma unroll
        for (int r = 0; r < 4; ++r) {
            const float mnew = fmaxf(m_run[r], mx[r]);
            alpha[r] = __expf(m_run[r] - mnew);
            m_run[r] = mnew;
            pl[r] = 0.f;
        }

        short pb[4][4];
        #pragma unroll
        for (int nt = 0; nt < 4; ++nt)
            #pragma unroll
            for (int r = 0; r < 4; ++r) {
                const float p = __expf(sv[nt][r] - m_run[r]);
                const unsigned short b = f2bf(p);
                pb[nt][r] = (short)b;
                pl[r] += __builtin_bit_cast(float, (unsigned int)b << 16);
            }
        #pragma unroll
        for (int r = 0; r < 4; ++r) {
            pl[r] += __shfl_xor(pl[r], 1, 16);
            pl[r] += __shfl_xor(pl[r], 2, 16);
            pl[r] += __shfl_xor(pl[r], 4, 16);
            pl[r] += __shfl_xor(pl[r], 8, 16);
            l_run[r] = l_run[r] * alpha[r] + pl[r];
        }
        #pragma unroll
        for (int d = 0; d < 8; ++d)
            #pragma unroll
            for (int r = 0; r < 4; ++r)
                oacc[d][r] *= alpha[r];

        #pragma unroll
        for (int nt = 0; nt < 4; ++nt)
            #pragma unroll
            for (int r = 0; r < 4; ++r)
                pw[(quad * 4 + r) * PLD + nt * 16 + l16] = pb[nt][r];

        bf16x8 pf[2];
        #pragma unroll
        for (int ks = 0; ks < 2; ++ks) {
            const s16x4 lo = *(const s16x4*)&pw[l16 * PLD + ks * 32 + quad * 8];
            const s16x4 hi = *(const s16x4*)&pw[l16 * PLD + ks * 32 + quad * 8 + 4];
            pf[ks] = __builtin_shufflevector(lo, hi, 0, 1, 2, 3, 4, 5, 6, 7);
        }

        #pragma unroll
        for (int dt = 0; dt < 8; ++dt) {
            const int drow = dt * 16 + l16;
            const int tsw  = (drow >> 2) & 7;
            #pragma unroll
            for (int ks = 0; ks < 2; ++ks) {
                const bf16x8 vf =
                    *(const bf16x8*)&vt_lds[drow * VLD + (((4 * ks + quad) ^ tsw) * 8)];
                oacc[dt] = __builtin_amdgcn_mfma_f32_16x16x32_bf16(pf[ks], vf, oacc[dt], 0, 0, 0);
            }
        }
    }

    const int orow0 = q0 + wave * 16 + quad * 4;
    #pragma unroll
    for (int r = 0; r < 4; ++r) {
        const float inv = 1.0f / l_run[r];
        float* orow = outg + (size_t)(orow0 + r) * HD + l16;
        #pragma unroll
        for (int d = 0; d < 8; ++d)
            orow[d * 16] = oacc[d][r] * inv;
    }
}

extern "C" void kernel_launch(void* const* d_in, const int* in_sizes, int n_in,
                              void* d_out, int out_size, void* d_ws, size_t ws_size,
                              hipStream_t stream) {
    const float* q    = (const float*)d_in[0];
    const float* k    = (const float*)d_in[1];
    const float* v    = (const float*)d_in[2];
    const float* mask = (const float*)d_in[3];
    float* out = (float*)d_out;

    const size_t need = (size_t)2 * NBH * NT * TILE_SH * sizeof(short); // 64 MB
    dim3 grid(NBH, S_LEN / BQ);
    if (d_ws != nullptr && ws_size >= need) {
        short* wsk = (short*)d_ws;
        short* wsv = wsk + (size_t)NBH * NT * TILE_SH;
        dim3 pgrid(NT, NBH, 2);
        prep_kernel<<<pgrid, 256, 0, stream>>>(k, v, wsk, wsv);
        fattn_ws_kernel<<<grid, 256, 0, stream>>>(wsk, wsv, q, mask, out);
    } else {
        fattn_legacy<<<grid, 256, 0, stream>>>(q, k, v, mask, out);
    }
}

// Round 6
// 505.145 us; speedup vs baseline: 1.1554x; 1.0212x over previous
//
#include <hip/hip_runtime.h>

// Flash-attention fwd, B=4 H=16 S=2048 D=128, fp32 in/out, bf16 MFMA compute.
// Round 8: occupancy via bigger blocks. Kernel is latency-bound (no pipe >40%,
// 3 waves/SIMD). 8-wave (512-thread) blocks share one K/V staging: BQ=128,
// grid (64,16), LDS 57856 B -> 2 blocks/CU = 16 waves/CU = 4 waves/SIMD
// (VGPR=72 allows exactly 4/SIMD; we were LDS-capped at 3). Staging DMA per
// unit work halves. P-exchange scratch: waves 0-3 use the idle K half (dead
// during the exchange, as proven in rounds 6-7), waves 4-7 use a dedicated
// 8704 B buffer. Per-wave arithmetic/order/rounding UNCHANGED from round 7
// -> absmax must stay exactly 0.0078125.

#define S_LEN 2048
#define HD 128
#define BK 64
#define NT (S_LEN / BK)          // 32
#define TILE_SH (BK * HD)        // 8192 shorts = 16 KB per staged tile image
#define PLD 68                   // P scratch row stride -> conflict-free
#define NBH 64

typedef __attribute__((ext_vector_type(8))) short bf16x8;
typedef __attribute__((ext_vector_type(4))) float f32x4;
typedef __attribute__((ext_vector_type(4))) short s16x4;

static __device__ __forceinline__ unsigned short f2bf(float f) {
    unsigned int u = __builtin_bit_cast(unsigned int, f);
    u += 0x7fffu + ((u >> 16) & 1u);   // round-to-nearest-even
    return (unsigned short)(u >> 16);
}

// global -> LDS direct DMA, 16B per lane; LDS dest = wave-uniform base + lane*16
static __device__ __forceinline__ void gload16(const short* g, short* l) {
    __builtin_amdgcn_global_load_lds(
        (const __attribute__((address_space(1))) unsigned int*)(const void*)g,
        (__attribute__((address_space(3))) unsigned int*)(void*)l,
        16, 0, 0);
}

// ---------------------------------------------------------------------------
// Prepass: build bf16 tile images in workspace (unchanged; ~54 us, near its
// HBM floor).
//   K image [bh][kt][row 0..63][cb 0..15][8]: phys block cb holds logical
//     block cb^(row&7) of K[row] (8 bf16 each).
//   V image [bh][kt][d 0..127][cb 0..7][8]: phys block cb holds
//     V[kt*64 + ((cb^(d&7))*8) .. +8][d].
// ---------------------------------------------------------------------------
__global__ __launch_bounds__(256)
void prep_kernel(const float* __restrict__ kg0, const float* __restrict__ vg0,
                 short* __restrict__ wsk, short* __restrict__ wsv)
{
    const int kt = blockIdx.x;
    const int bh = blockIdx.y;
    const int t  = threadIdx.x;
    if (blockIdx.z == 0) {
        const float* src = kg0 + ((size_t)bh * S_LEN + kt * BK) * HD;
        short* dst = wsk + ((size_t)bh * NT + kt) * TILE_SH;
        #pragma unroll
        for (int i = 0; i < 4; ++i) {
            const int c = t + 256 * i;
            const int row = c >> 4, cb = c & 15;
            const float* s = src + row * HD + ((cb ^ (row & 7)) << 3);
            const f32x4 a = *(const f32x4*)s;
            const f32x4 b = *(const f32x4*)(s + 4);
            bf16x8 o;
            #pragma unroll
            for (int j = 0; j < 4; ++j) {
                o[j]     = (short)f2bf(a[j]);
                o[j + 4] = (short)f2bf(b[j]);
            }
            *(bf16x8*)(dst + (size_t)c * 8) = o;
        }
    } else {
        __shared__ short lv[BK * 136];    // [kk][d] staging for the transpose
        const float* src = vg0 + ((size_t)bh * S_LEN + kt * BK) * HD;
        short* dst = wsv + ((size_t)bh * NT + kt) * TILE_SH;
        #pragma unroll
        for (int p = 0; p < 2; ++p) {
            const int kk = (t >> 3) + p * 32;
            const int d0 = (t & 7) * 16;
            const float* s = src + kk * HD + d0;
            #pragma unroll
            for (int g = 0; g < 2; ++g) {
                const f32x4 a = *(const f32x4*)(s + g * 8);
                const f32x4 b = *(const f32x4*)(s + g * 8 + 4);
                bf16x8 o;
                #pragma unroll
                for (int j = 0; j < 4; ++j) {
                    o[j]     = (short)f2bf(a[j]);
                    o[j + 4] = (short)f2bf(b[j]);
                }
                *(bf16x8*)&lv[kk * 136 + d0 + g * 8] = o;
            }
        }
        __syncthreads();
        #pragma unroll
        for (int i = 0; i < 4; ++i) {
            const int c = t + 256 * i;
            const int d = c >> 3, cb = c & 7;
            const int kk0 = (cb ^ (d & 7)) << 3;
            bf16x8 o;
            #pragma unroll
            for (int j = 0; j < 8; ++j) o[j] = lv[(kk0 + j) * 136 + d];
            *(bf16x8*)(dst + (size_t)c * 8) = o;
        }
    }
}

// ---------------------------------------------------------------------------
// Main kernel: 8 waves / 512 threads, BQ=128, 57856 B LDS => 2 blocks/CU
// (16 waves/CU = 4 waves/SIMD, the VGPR-allowed max at VGPR=72).
// ---------------------------------------------------------------------------
__global__ __launch_bounds__(512, 4)
void fattn_ws_kernel(const short* __restrict__ wsk, const short* __restrict__ wsv,
                     const float* __restrict__ qg0, const float* __restrict__ maskg,
                     float* __restrict__ outg0)
{
    // k_lds double-buffers the K tile image; the idle half serves as the
    // P-exchange scratch for waves 0-3 (dead between 2nd barrier of iter kt-1
    // and the K[kt+1] DMA issued after the 2nd barrier of iter kt).
    __shared__ short k_lds[2][TILE_SH];
    __shared__ short v_lds[TILE_SH];        // single-buffered V^T tile image
    __shared__ short p_hi[4 * 16 * PLD];    // P scratch for waves 4-7

    const int tid  = threadIdx.x;
    const int wave = tid >> 6;              // 0..7
    const int lane = tid & 63;
    const int quad = lane >> 4;
    const int l16  = lane & 15;

    const int bh = blockIdx.x;              // fast dim: co-resident blocks share K/V
    const int q0 = blockIdx.y * 128;        // BQ = 128

    const float* qg   = qg0 + (size_t)bh * S_LEN * HD;
    float*       outg = outg0 + (size_t)bh * S_LEN * HD;
    const short* ktiles = wsk + (size_t)bh * NT * TILE_SH;
    const short* vtiles = wsv + (size_t)bh * NT * TILE_SH;

    const int soff = tid * 8;               // per-thread offset in tile (shorts)
    const int loff = (tid & ~63) * 8;       // wave-uniform LDS offset (shorts)

    // issue K tile 0 immediately (drained by first barrier); 512 thr -> 2 rounds
    #pragma unroll
    for (int p = 0; p < 2; ++p)
        gload16(ktiles + p * 4096 + soff, &k_lds[0][p * 4096 + loff]);

    // Q A-fragments: m = l16, k = ks*32 + quad*8 + j  (held for whole kernel)
    bf16x8 qf[4];
    {
        const float* qrow = qg + (size_t)(q0 + wave * 16 + l16) * HD + quad * 8;
        #pragma unroll
        for (int ks = 0; ks < 4; ++ks) {
            const f32x4 a = *(const f32x4*)(qrow + ks * 32);
            const f32x4 b = *(const f32x4*)(qrow + ks * 32 + 4);
            #pragma unroll
            for (int j = 0; j < 4; ++j) {
                qf[ks][j]     = (short)f2bf(a[j]);
                qf[ks][j + 4] = (short)f2bf(b[j]);
            }
        }
    }

    float m_run[4], l_run[4];
    f32x4 oacc[8];
    #pragma unroll
    for (int r = 0; r < 4; ++r) { m_run[r] = -3.0e38f; l_run[r] = 0.0f; }
    #pragma unroll
    for (int d = 0; d < 8; ++d) oacc[d] = (f32x4){0.f, 0.f, 0.f, 0.f};

    const float LOG2E  = 1.4426950408889634f;
    const float scale2 = 0.088388347648318447f * LOG2E;  // (1/sqrt(128))*log2e
    const float* mrow = maskg + (size_t)(q0 + wave * 16 + quad * 4) * S_LEN + l16;

    float mpre[4][4];
    #pragma unroll
    for (int nt = 0; nt < 4; ++nt)
        #pragma unroll
        for (int r = 0; r < 4; ++r)
            mpre[nt][r] = mrow[(size_t)r * S_LEN + nt * 16] * LOG2E;

    // LDS fragment-read bases (shorts). Swizzled block index decomposes into
    // base ^ (ks-bit) + immediates -> zero per-iteration address VALU.
    const int kb0 = l16 * 128 + ((quad ^ (l16 & 3)) << 3) + (((l16 >> 2) & 1) << 5);
    const int kb1 = kb0 ^ 32;
    const int vb0 = l16 * 64  + ((quad ^ (l16 & 3)) << 3) + (((l16 >> 2) & 1) << 5);
    const int vb1 = vb0 ^ 32;

    // P scratch bases: waves 0-3 in the idle K half (kt-parity dependent),
    // waves 4-7 in the dedicated buffer (parity-independent).
    short* const pwA = (wave < 4) ? &k_lds[1][wave * 16 * PLD]
                                  : &p_hi[(wave - 4) * 16 * PLD];
    short* const pwB = (wave < 4) ? &k_lds[0][wave * 16 * PLD]
                                  : &p_hi[(wave - 4) * 16 * PLD];

    for (int kt = 0; kt < NT; ++kt) {
        const short* kcur = k_lds[kt & 1];
        short* const pw = (kt & 1) ? pwB : pwA;   // idle K half (or p_hi)

        asm volatile("s_waitcnt vmcnt(0)" ::: "memory");  // K[kt] DMA landed
        __syncthreads();

        // issue V[kt]; latency hidden under QK^T + softmax
        #pragma unroll
        for (int p = 0; p < 2; ++p)
            gload16(vtiles + (size_t)kt * TILE_SH + p * 4096 + soff,
                    &v_lds[p * 4096 + loff]);

        // ---- S = Q K^T (log2 domain) ----
        f32x4 sf[4];
        __builtin_amdgcn_s_setprio(1);
        #pragma unroll
        for (int nt = 0; nt < 4; ++nt) {
            f32x4 acc = (f32x4){0.f, 0.f, 0.f, 0.f};
            #pragma unroll
            for (int ks = 0; ks < 4; ++ks) {
                const bf16x8 kf = *(const bf16x8*)
                    &kcur[((ks & 1) ? kb1 : kb0) + (ks >> 1) * 64 + nt * 2048];
                acc = __builtin_amdgcn_mfma_f32_16x16x32_bf16(qf[ks], kf, acc, 0, 0, 0);
            }
            sf[nt] = acc;
        }
        __builtin_amdgcn_s_setprio(0);

        float sv[4][4];
        float mx[4] = {-3.0e38f, -3.0e38f, -3.0e38f, -3.0e38f};
        #pragma unroll
        for (int nt = 0; nt < 4; ++nt)
            #pragma unroll
            for (int r = 0; r < 4; ++r) {
                const float s = sf[nt][r] * scale2 + mpre[nt][r];  // log2 units
                sv[nt][r] = s;
                mx[r] = fmaxf(mx[r], s);
            }

        #pragma unroll
        for (int r = 0; r < 4; ++r) {
            mx[r] = fmaxf(mx[r], __shfl_xor(mx[r], 1, 16));
            mx[r] = fmaxf(mx[r], __shfl_xor(mx[r], 2, 16));
            mx[r] = fmaxf(mx[r], __shfl_xor(mx[r], 4, 16));
            mx[r] = fmaxf(mx[r], __shfl_xor(mx[r], 8, 16));
        }

        // ---- defer-max: rescale only when max materially grows (p <= 2^8) ----
        const bool needl = (mx[0] > m_run[0] + 8.0f) | (mx[1] > m_run[1] + 8.0f) |
                           (mx[2] > m_run[2] + 8.0f) | (mx[3] > m_run[3] + 8.0f);
        const int upd = __any((int)needl);
        float alpha[4];
        if (upd) {
            #pragma unroll
            for (int r = 0; r < 4; ++r) {
                const float mnew = fmaxf(m_run[r], mx[r]);
                alpha[r] = __builtin_amdgcn_exp2f(m_run[r] - mnew);
                m_run[r] = mnew;
            }
        }

        // ---- P = exp2(S - m) -> bf16 (rounded l matches PV) ----
        float pl[4] = {0.f, 0.f, 0.f, 0.f};
        short pb[4][4];
        #pragma unroll
        for (int nt = 0; nt < 4; ++nt)
            #pragma unroll
            for (int r = 0; r < 4; ++r) {
                const float p = __builtin_amdgcn_exp2f(sv[nt][r] - m_run[r]);
                const unsigned short b = f2bf(p);
                pb[nt][r] = (short)b;
                pl[r] += __builtin_bit_cast(float, (unsigned int)b << 16);
            }
        #pragma unroll
        for (int r = 0; r < 4; ++r) {
            pl[r] += __shfl_xor(pl[r], 1, 16);
            pl[r] += __shfl_xor(pl[r], 2, 16);
            pl[r] += __shfl_xor(pl[r], 4, 16);
            pl[r] += __shfl_xor(pl[r], 8, 16);
        }
        if (upd) {
            #pragma unroll
            for (int r = 0; r < 4; ++r) l_run[r] = l_run[r] * alpha[r] + pl[r];
            #pragma unroll
            for (int d = 0; d < 8; ++d)
                #pragma unroll
                for (int r = 0; r < 4; ++r) oacc[d][r] *= alpha[r];
        } else {
            #pragma unroll
            for (int r = 0; r < 4; ++r) l_run[r] += pl[r];
        }

        // ---- P: C-layout -> scratch LDS -> A-layout (per-wave, no barrier) ----
        #pragma unroll
        for (int nt = 0; nt < 4; ++nt)
            #pragma unroll
            for (int r = 0; r < 4; ++r)
                pw[(quad * 4 + r) * PLD + nt * 16 + l16] = pb[nt][r];

        bf16x8 pf[2];
        #pragma unroll
        for (int ks = 0; ks < 2; ++ks) {
            const s16x4 lo = *(const s16x4*)&pw[l16 * PLD + ks * 32 + quad * 8];
            const s16x4 hi = *(const s16x4*)&pw[l16 * PLD + ks * 32 + quad * 8 + 4];
            pf[ks] = __builtin_shufflevector(lo, hi, 0, 1, 2, 3, 4, 5, 6, 7);
        }

        asm volatile("s_waitcnt vmcnt(0)" ::: "memory");  // V[kt] DMA landed
        __syncthreads();

        // issue K[kt+1] (overwrites waves-0..3 P scratch -- reads completed)
        const int nk = (kt + 1) & (NT - 1);
        #pragma unroll
        for (int p = 0; p < 2; ++p)
            gload16(ktiles + (size_t)nk * TILE_SH + p * 4096 + soff,
                    &k_lds[nk & 1][p * 4096 + loff]);
        const int nb = nk * BK;
        #pragma unroll
        for (int nt = 0; nt < 4; ++nt)
            #pragma unroll
            for (int r = 0; r < 4; ++r)
                mpre[nt][r] = mrow[(size_t)r * S_LEN + nb + nt * 16] * LOG2E;

        // ---- O += P V ----
        __builtin_amdgcn_s_setprio(1);
        #pragma unroll
        for (int dt = 0; dt < 8; ++dt) {
            #pragma unroll
            for (int ks = 0; ks < 2; ++ks) {
                const bf16x8 vf = *(const bf16x8*)&v_lds[(ks ? vb1 : vb0) + dt * 1024];
                oacc[dt] = __builtin_amdgcn_mfma_f32_16x16x32_bf16(pf[ks], vf, oacc[dt], 0, 0, 0);
            }
        }
        __builtin_amdgcn_s_setprio(0);
    }

    // ---- epilogue: normalize and store ----
    const int orow0 = q0 + wave * 16 + quad * 4;
    #pragma unroll
    for (int r = 0; r < 4; ++r) {
        const float inv = 1.0f / l_run[r];
        float* orow = outg + (size_t)(orow0 + r) * HD + l16;
        #pragma unroll
        for (int d = 0; d < 8; ++d)
            orow[d * 16] = oacc[d][r] * inv;
    }
}

// ---------------------------------------------------------------------------
// Legacy kernel (round 3, proven) — fallback if workspace is too small.
// ---------------------------------------------------------------------------
#define KLD 136
#define VLD 72

__global__ __launch_bounds__(256, 2)
void fattn_legacy(const float* __restrict__ qg0, const float* __restrict__ kg0,
                  const float* __restrict__ vg0, const float* __restrict__ maskg,
                  float* __restrict__ outg0)
{
    __shared__ short k_lds[BK * KLD];
    __shared__ short vt_lds[HD * VLD];
    __shared__ short p_lds[4 * 16 * PLD];

    const int tid  = threadIdx.x;
    const int wave = tid >> 6;
    const int lane = tid & 63;
    const int quad = lane >> 4;
    const int l16  = lane & 15;

    const int bh = blockIdx.x;
    const int q0 = blockIdx.y * 64;

    const float* qg   = qg0 + (size_t)bh * S_LEN * HD;
    const float* kg   = kg0 + (size_t)bh * S_LEN * HD;
    const float* vg   = vg0 + (size_t)bh * S_LEN * HD;
    float*       outg = outg0 + (size_t)bh * S_LEN * HD;

    bf16x8 qf[4];
    {
        const float* qrow = qg + (size_t)(q0 + wave * 16 + l16) * HD + quad * 8;
        #pragma unroll
        for (int ks = 0; ks < 4; ++ks) {
            const f32x4 a = *(const f32x4*)(qrow + ks * 32);
            const f32x4 b = *(const f32x4*)(qrow + ks * 32 + 4);
            #pragma unroll
            for (int j = 0; j < 4; ++j) {
                qf[ks][j]     = (short)f2bf(a[j]);
                qf[ks][j + 4] = (short)f2bf(b[j]);
            }
        }
    }

    float m_run[4], l_run[4];
    f32x4 oacc[8];
    #pragma unroll
    for (int r = 0; r < 4; ++r) { m_run[r] = -3.0e38f; l_run[r] = 0.0f; }
    #pragma unroll
    for (int d = 0; d < 8; ++d) oacc[d] = (f32x4){0.f, 0.f, 0.f, 0.f};

    const float scale = 0.088388347648318447f;
    const float* mrow = maskg + (size_t)(q0 + wave * 16 + quad * 4) * S_LEN + l16;

    const int rr = tid >> 5;
    const int cc = tid & 31;
    short* const pw = &p_lds[wave * 16 * PLD];

    f32x4 kpre[8], vpre[8];
    float mpre[4][4];
    #pragma unroll
    for (int it = 0; it < 8; ++it)
        kpre[it] = *(const f32x4*)(kg + (size_t)(rr + 8 * it) * HD + cc * 4);
    #pragma unroll
    for (int it = 0; it < 8; ++it)
        vpre[it] = *(const f32x4*)(vg + (size_t)(rr * 8 + it) * HD + cc * 4);
    #pragma unroll
    for (int nt = 0; nt < 4; ++nt)
        #pragma unroll
        for (int r = 0; r < 4; ++r)
            mpre[nt][r] = mrow[(size_t)r * S_LEN + nt * 16];

    for (int kt = 0; kt < NT; ++kt) {
        __syncthreads();

        #pragma unroll
        for (int it = 0; it < 8; ++it) {
            s16x4 kb4;
            kb4[0] = (short)f2bf(kpre[it][0]); kb4[1] = (short)f2bf(kpre[it][1]);
            kb4[2] = (short)f2bf(kpre[it][2]); kb4[3] = (short)f2bf(kpre[it][3]);
            *(s16x4*)&k_lds[(rr + 8 * it) * KLD + cc * 4] = kb4;
        }
        #pragma unroll
        for (int i = 0; i < 4; ++i) {
            bf16x8 col;
            #pragma unroll
            for (int it = 0; it < 8; ++it)
                col[it] = (short)f2bf(vpre[it][i]);
            const int d = cc * 4 + i;
            const int pblk = rr ^ (cc & 7);
            *(bf16x8*)&vt_lds[d * VLD + pblk * 8] = col;
        }
        __syncthreads();

        const int nb = (kt + 1 < NT) ? (kt + 1) * BK : 0;
        #pragma unroll
        for (int it = 0; it < 8; ++it)
            kpre[it] = *(const f32x4*)(kg + (size_t)(nb + rr + 8 * it) * HD + cc * 4);
        #pragma unroll
        for (int it = 0; it < 8; ++it)
            vpre[it] = *(const f32x4*)(vg + (size_t)(nb + rr * 8 + it) * HD + cc * 4);

        f32x4 sf[4];
        #pragma unroll
        for (int nt = 0; nt < 4; ++nt) {
            f32x4 acc = (f32x4){0.f, 0.f, 0.f, 0.f};
            #pragma unroll
            for (int ks = 0; ks < 4; ++ks) {
                const bf16x8 kf =
                    *(const bf16x8*)&k_lds[(nt * 16 + l16) * KLD + ks * 32 + quad * 8];
                acc = __builtin_amdgcn_mfma_f32_16x16x32_bf16(qf[ks], kf, acc, 0, 0, 0);
            }
            sf[nt] = acc;
        }

        float sv[4][4];
        float mx[4] = {-3.0e38f, -3.0e38f, -3.0e38f, -3.0e38f};
        #pragma unroll
        for (int nt = 0; nt < 4; ++nt)
            #pragma unroll
            for (int r = 0; r < 4; ++r) {
                const float s = sf[nt][r] * scale + mpre[nt][r];
                sv[nt][r] = s;
                mx[r] = fmaxf(mx[r], s);
            }

        #pragma unroll
        for (int nt = 0; nt < 4; ++nt)
            #pragma unroll
            for (int r = 0; r < 4; ++r)
                mpre[nt][r] = mrow[(size_t)r * S_LEN + nb + nt * 16];

        #pragma unroll
        for (int r = 0; r < 4; ++r) {
            mx[r] = fmaxf(mx[r], __shfl_xor(mx[r], 1, 16));
            mx[r] = fmaxf(mx[r], __shfl_xor(mx[r], 2, 16));
            mx[r] = fmaxf(mx[r], __shfl_xor(mx[r], 4, 16));
            mx[r] = fmaxf(mx[r], __shfl_xor(mx[r], 8, 16));
        }

        float alpha[4], pl[4];
        #pragma unroll
        for (int r = 0; r < 4; ++r) {
            const float mnew = fmaxf(m_run[r], mx[r]);
            alpha[r] = __expf(m_run[r] - mnew);
            m_run[r] = mnew;
            pl[r] = 0.f;
        }

        short pb[4][4];
        #pragma unroll
        for (int nt = 0; nt < 4; ++nt)
            #pragma unroll
            for (int r = 0; r < 4; ++r) {
                const float p = __expf(sv[nt][r] - m_run[r]);
                const unsigned short b = f2bf(p);
                pb[nt][r] = (short)b;
                pl[r] += __builtin_bit_cast(float, (unsigned int)b << 16);
            }
        #pragma unroll
        for (int r = 0; r < 4; ++r) {
            pl[r] += __shfl_xor(pl[r], 1, 16);
            pl[r] += __shfl_xor(pl[r], 2, 16);
            pl[r] += __shfl_xor(pl[r], 4, 16);
            pl[r] += __shfl_xor(pl[r], 8, 16);
            l_run[r] = l_run[r] * alpha[r] + pl[r];
        }
        #pragma unroll
        for (int d = 0; d < 8; ++d)
            #pragma unroll
            for (int r = 0; r < 4; ++r)
                oacc[d][r] *= alpha[r];

        #pragma unroll
        for (int nt = 0; nt < 4; ++nt)
            #pragma unroll
            for (int r = 0; r < 4; ++r)
                pw[(quad * 4 + r) * PLD + nt * 16 + l16] = pb[nt][r];

        bf16x8 pf[2];
        #pragma unroll
        for (int ks = 0; ks < 2; ++ks) {
            const s16x4 lo = *(const s16x4*)&pw[l16 * PLD + ks * 32 + quad * 8];
            const s16x4 hi = *(const s16x4*)&pw[l16 * PLD + ks * 32 + quad * 8 + 4];
            pf[ks] = __builtin_shufflevector(lo, hi, 0, 1, 2, 3, 4, 5, 6, 7);
        }

        #pragma unroll
        for (int dt = 0; dt < 8; ++dt) {
            const int drow = dt * 16 + l16;
            const int tsw  = (drow >> 2) & 7;
            #pragma unroll
            for (int ks = 0; ks < 2; ++ks) {
                const bf16x8 vf =
                    *(const bf16x8*)&vt_lds[drow * VLD + (((4 * ks + quad) ^ tsw) * 8)];
                oacc[dt] = __builtin_amdgcn_mfma_f32_16x16x32_bf16(pf[ks], vf, oacc[dt], 0, 0, 0);
            }
        }
    }

    const int orow0 = q0 + wave * 16 + quad * 4;
    #pragma unroll
    for (int r = 0; r < 4; ++r) {
        const float inv = 1.0f / l_run[r];
        float* orow = outg + (size_t)(orow0 + r) * HD + l16;
        #pragma unroll
        for (int d = 0; d < 8; ++d)
            orow[d * 16] = oacc[d][r] * inv;
    }
}

extern "C" void kernel_launch(void* const* d_in, const int* in_sizes, int n_in,
                              void* d_out, int out_size, void* d_ws, size_t ws_size,
                              hipStream_t stream) {
    const float* q    = (const float*)d_in[0];
    const float* k    = (const float*)d_in[1];
    const float* v    = (const float*)d_in[2];
    const float* mask = (const float*)d_in[3];
    float* out = (float*)d_out;

    const size_t need = (size_t)2 * NBH * NT * TILE_SH * sizeof(short); // 64 MB
    if (d_ws != nullptr && ws_size >= need) {
        short* wsk = (short*)d_ws;
        short* wsv = wsk + (size_t)NBH * NT * TILE_SH;
        dim3 pgrid(NT, NBH, 2);
        prep_kernel<<<pgrid, 256, 0, stream>>>(k, v, wsk, wsv);
        dim3 grid(NBH, S_LEN / 128);   // 8-wave blocks, BQ=128
        fattn_ws_kernel<<<grid, 512, 0, stream>>>(wsk, wsv, q, mask, out);
    } else {
        dim3 grid(NBH, S_LEN / 64);
        fattn_legacy<<<grid, 256, 0, stream>>>(q, k, v, mask, out);
    }
}